// Round 4
// baseline (2789.699 us; speedup 1.0000x reference)
//
#include <hip/hip_runtime.h>

#define BB  8
#define NP  2048
#define KNB 20
#define SS  (NP * KNB)   // 40960 spatial per batch for layers 1-4

typedef unsigned short bf16_t;

static __device__ __forceinline__ float bf2f(bf16_t u) {
    return __uint_as_float(((unsigned)u) << 16);
}
static __device__ __forceinline__ bf16_t f2bf(float f) {
    unsigned u = __float_as_uint(f);
    return (bf16_t)((u + 0x7fffu + ((u >> 16) & 1u)) >> 16);   // RNE
}

// ---- order-preserving float<->uint for atomicMax pooling ----
static __device__ __forceinline__ unsigned fkey(float f) {
    unsigned u = __float_as_uint(f);
    return (u & 0x80000000u) ? ~u : (u | 0x80000000u);
}
static __device__ __forceinline__ float funkey(unsigned k) {
    return (k & 0x80000000u) ? __uint_as_float(k ^ 0x80000000u) : __uint_as_float(~k);
}

template <typename T> struct V4;
template <> struct V4<float> {
    using t = float4;
    static __device__ __forceinline__ float4 cvt(float4 v) { return v; }
};
template <> struct V4<bf16_t> {
    using t = ushort4;
    static __device__ __forceinline__ float4 cvt(ushort4 v) {
        return make_float4(bf2f(v.x), bf2f(v.y), bf2f(v.z), bf2f(v.w));
    }
};

// ---- zero fill (pool keys + stats, contiguous region) ----
__global__ __launch_bounds__(256) void zero_kernel(float* __restrict__ p, int n4) {
    int t = blockIdx.x * 256 + threadIdx.x;
    if (t < n4) ((float4*)p)[t] = make_float4(0.f, 0.f, 0.f, 0.f);
}

// ==== kNN: 16 points x 16 segments per block, top-20 in explicit scalar
//      registers (no arrays -> no scratch spill), 16-lane shfl merge. ====
#define KDECL(t) float v##t = -3.4e38f; int j##t = 0;
#define KSTEP(t, p) \
    { if (v > v##p) { v##t = v##p; j##t = j##p; } \
      else if (v > v##t) { v##t = v; j##t = j; } }
#define KSHIFT(t, n) v##t = v##n; j##t = j##n;

__global__ __launch_bounds__(256) void knn_kernel(const float* __restrict__ x,
                                                  int* __restrict__ idx) {
    __shared__ float4 tile[2064];    // 2048 + swizzle pad (j + (j>>7)), 33 KB
    const int tid  = threadIdx.x;
    const int b    = blockIdx.x >> 7;     // 128 blocks per batch
    const int pblk = blockIdx.x & 127;
    const int pl   = tid >> 4;            // local point 0..15
    const int seg  = tid & 15;            // segment 0..15 (128 j's each)
    const int i    = pblk * 16 + pl;
    const float* xb = x + (size_t)b * 3 * NP;

    for (int j = tid; j < NP; j += 256) {
        float a0 = xb[j], a1 = xb[NP + j], a2 = xb[2 * NP + j];
        tile[j + (j >> 7)] = make_float4(a0, a1, a2, a0 * a0 + a1 * a1 + a2 * a2);
    }
    __syncthreads();
    const float4 me = tile[i + (i >> 7)];

    KDECL(0)  KDECL(1)  KDECL(2)  KDECL(3)  KDECL(4)
    KDECL(5)  KDECL(6)  KDECL(7)  KDECL(8)  KDECL(9)
    KDECL(10) KDECL(11) KDECL(12) KDECL(13) KDECL(14)
    KDECL(15) KDECL(16) KDECL(17) KDECL(18) KDECL(19)

    const int jbase = seg * 128;
    const float4* tseg = &tile[seg * 129];   // phys base for this segment
    for (int t = 0; t < 128; ++t) {
        float4 p = tseg[t];
        float d = me.x * p.x + me.y * p.y + me.z * p.z;
        float v = 2.0f * d - me.w - p.w;     // same formula as reference
        int j = jbase + t;
        if (v > v19) {
            KSTEP(19,18) KSTEP(18,17) KSTEP(17,16) KSTEP(16,15) KSTEP(15,14)
            KSTEP(14,13) KSTEP(13,12) KSTEP(12,11) KSTEP(11,10) KSTEP(10,9)
            KSTEP(9,8)   KSTEP(8,7)   KSTEP(7,6)   KSTEP(6,5)   KSTEP(5,4)
            KSTEP(4,3)   KSTEP(3,2)   KSTEP(2,1)   KSTEP(1,0)
            if (v > v0) { v0 = v; j0 = j; }
        }
    }

    // merge 16 sorted-desc lists of 20 across the 16 lanes of this point
    int* o = idx + ((size_t)b * NP + i) * KNB;
    float hv = v0; int hj = j0;
    for (int r = 0; r < KNB; ++r) {
        float mv = hv; int mj = hj;
#pragma unroll
        for (int s = 1; s <= 8; s <<= 1) {
            float ov = __shfl_xor(mv, s, 64);
            int   oj = __shfl_xor(mj, s, 64);
            if (ov > mv || (ov == mv && oj < mj)) { mv = ov; mj = oj; }
        }
        if (seg == 0) o[r] = mj;
        if (hv == mv && hj == mj) {          // unique winner pops (j unique)
            KSHIFT(0,1)   KSHIFT(1,2)   KSHIFT(2,3)   KSHIFT(3,4)   KSHIFT(4,5)
            KSHIFT(5,6)   KSHIFT(6,7)   KSHIFT(7,8)   KSHIFT(8,9)   KSHIFT(9,10)
            KSHIFT(10,11) KSHIFT(11,12) KSHIFT(12,13) KSHIFT(13,14) KSHIFT(14,15)
            KSHIFT(15,16) KSHIFT(16,17) KSHIFT(17,18) KSHIFT(18,19)
            v19 = -3.4e38f; j19 = 0;
        }
        hv = v0; hj = j0;
    }
}

// ---- graph feature f[b, 0..5, n*K+k] = [nbr xyz, center xyz], bf16 ----
__global__ __launch_bounds__(256) void gather_kernel(const float* __restrict__ x,
                                                     const int* __restrict__ idx,
                                                     bf16_t* __restrict__ f) {
    int t = blockIdx.x * 256 + threadIdx.x;
    if (t >= BB * SS) return;
    int b = t / SS;
    int r = t - b * SS;
    int n = r / KNB;
    int j = idx[t];
    const float* xb = x + (size_t)b * 3 * NP;
    bf16_t* fb = f + (size_t)b * 6 * SS + r;
    fb[0]          = f2bf(xb[j]);
    fb[SS]         = f2bf(xb[NP + j]);
    fb[2 * SS]     = f2bf(xb[2 * NP + j]);
    fb[3 * SS]     = f2bf(xb[n]);
    fb[4 * SS]     = f2bf(xb[NP + n]);
    fb[5 * SS]     = f2bf(xb[2 * NP + n]);
}

// ---- tiled 1x1 conv. Block: 64 co x 256 s. Thread: 16 co x 4 s.
//      __launch_bounds__(256,2): cap at 2 blocks/CU -> <=256 VGPRs so the
//      64-float accumulator tile stays in registers (R3: default heuristic
//      capped at 60 VGPRs and spilled acc to scratch -> 780us/conv).
template <typename TIN, typename TOUT, bool INBN, bool POOL, bool STORE>
__global__ __launch_bounds__(256, 2) void conv_tiled(
    const TIN* __restrict__ H, const float* __restrict__ Wt,
    const float* __restrict__ abin,
    TOUT* __restrict__ Y, unsigned* __restrict__ Mx, int chofs,
    float* __restrict__ stats, int Cin, int Cout, int Ssz) {
    __shared__ __align__(16) float wl[16][64];
    const int tid = threadIdx.x;
    const int sx  = tid & 63;        // lane (wave == co-subtile: cs uniform/wave)
    const int cs  = tid >> 6;
    const int s0  = blockIdx.x * 256 + sx * 4;
    const int cob = blockIdx.y * 64;
    const int b   = blockIdx.z;

    const TIN* h = H + (size_t)b * Cin * Ssz + s0;
    float acc[16][4];
#pragma unroll
    for (int r = 0; r < 16; ++r)
#pragma unroll
        for (int u = 0; u < 4; ++u) acc[r][u] = 0.f;

    auto body = [&](int c0, int cc) {
        typename V4<TIN>::t raw = *(const typename V4<TIN>::t*)(h + (size_t)(c0 + cc) * Ssz);
        float4 hv = V4<TIN>::cvt(raw);
        if constexpr (INBN) {
            float a = abin[c0 + cc], d = abin[Cin + c0 + cc];
            hv.x = fmaxf(fmaf(a, hv.x, d), 0.f);
            hv.y = fmaxf(fmaf(a, hv.y, d), 0.f);
            hv.z = fmaxf(fmaf(a, hv.z, d), 0.f);
            hv.w = fmaxf(fmaf(a, hv.w, d), 0.f);
        }
        const float4* wp = (const float4*)(&wl[cc][cs << 4]);
#pragma unroll
        for (int rq = 0; rq < 4; ++rq) {
            float4 wv = wp[rq];
            float wj[4] = {wv.x, wv.y, wv.z, wv.w};
#pragma unroll
            for (int j = 0; j < 4; ++j) {
                int r = (rq << 2) + j;
                acc[r][0] = fmaf(wj[j], hv.x, acc[r][0]);
                acc[r][1] = fmaf(wj[j], hv.y, acc[r][1]);
                acc[r][2] = fmaf(wj[j], hv.z, acc[r][2]);
                acc[r][3] = fmaf(wj[j], hv.w, acc[r][3]);
            }
        }
    };

    int c0 = 0;
    for (; c0 + 16 <= Cin; c0 += 16) {
        __syncthreads();
        for (int e = tid; e < (16 << 6); e += 256) {
            int cc = e >> 6, co = e & 63;
            wl[cc][co] = Wt[(size_t)(cob + co) * Cin + (c0 + cc)];
        }
        __syncthreads();
#pragma unroll
        for (int cc = 0; cc < 16; ++cc) body(c0, cc);
    }
    if (c0 < Cin) {
        const int chunk = Cin - c0;
        __syncthreads();
        for (int e = tid; e < (chunk << 6); e += 256) {
            int cc = e >> 6, co = e & 63;
            wl[cc][co] = Wt[(size_t)(cob + co) * Cin + (c0 + cc)];
        }
        __syncthreads();
        for (int cc = 0; cc < chunk; ++cc) body(c0, cc);
    }

    if constexpr (STORE) {
        TOUT* y = Y + ((size_t)b * Cout + cob + (cs << 4)) * Ssz + s0;
#pragma unroll
        for (int r = 0; r < 16; ++r) {
            if constexpr (sizeof(TOUT) == 2) {
                ushort4 o;
                o.x = f2bf(acc[r][0]); o.y = f2bf(acc[r][1]);
                o.z = f2bf(acc[r][2]); o.w = f2bf(acc[r][3]);
                *(ushort4*)((bf16_t*)y + (size_t)r * Ssz) = o;
            } else {
                *(float4*)((float*)y + (size_t)r * Ssz) =
                    make_float4(acc[r][0], acc[r][1], acc[r][2], acc[r][3]);
            }
        }
    }

    if constexpr (POOL) {
        const int n = s0 / KNB;           // 4 cols of a thread share one n
        int pn = __shfl_up(n, 1, 64);
        bool leader = (sx == 0) || (pn != n);
#pragma unroll
        for (int r = 0; r < 16; ++r) {
            float m = fmaxf(fmaxf(acc[r][0], acc[r][1]), fmaxf(acc[r][2], acc[r][3]));
#pragma unroll
            for (int o = 1; o <= 4; ++o) {   // group = <=5 consecutive lanes
                float om = __shfl_down(m, o, 64);
                int   on = __shfl_down(n, o, 64);
                if (on == n) m = fmaxf(m, om);
            }
            if (leader)
                atomicMax(&Mx[((size_t)b * 512 + chofs + cob + (cs << 4) + r) * NP + n],
                          fkey(m));
        }
    }

    // BN stats: wave reduce (wave == one 16-co subtile), then atomicAdd
#pragma unroll
    for (int r = 0; r < 16; ++r) {
        float sv = acc[r][0] + acc[r][1] + acc[r][2] + acc[r][3];
        float qv = acc[r][0] * acc[r][0] + acc[r][1] * acc[r][1] +
                   acc[r][2] * acc[r][2] + acc[r][3] * acc[r][3];
#pragma unroll
        for (int msk = 1; msk < 64; msk <<= 1) {
            sv += __shfl_xor(sv, msk, 64);
            qv += __shfl_xor(qv, msk, 64);
        }
        if (sx == 0) {
            atomicAdd(&stats[cob + (cs << 4) + r], sv);
            atomicAdd(&stats[Cout + cob + (cs << 4) + r], qv);
        }
    }
}

// ---- stats -> affine coefs: a = g*rsqrt(var+eps), d = b - mean*a ----
__global__ void bn_finalize_kernel(const float* __restrict__ stats,
                                   const float* __restrict__ g,
                                   const float* __restrict__ bt,
                                   float* __restrict__ ab, int C, float invM) {
    int c = blockIdx.x * 64 + threadIdx.x;
    if (c >= C) return;
    float mean = stats[c] * invM;
    float var  = fmaxf(stats[C + c] * invM - mean * mean, 0.f);
    float a = g[c] * rsqrtf(var + 1e-5f);
    ab[c] = a;
    ab[C + c] = fmaf(-mean, a, bt[c]);
}

// ---- decode pooled-max key, apply BN+ReLU, write float into xcat ----
__global__ __launch_bounds__(256) void pool_convert_kernel(float* __restrict__ xc,
                                                           const float* __restrict__ ab,
                                                           int C, int chofs) {
    int t = blockIdx.x * 256 + threadIdx.x;   // exact grid over B*C*NP
    int n = t & (NP - 1);
    int bc = t >> 11;
    int c = bc % C;
    int b = bc / C;
    size_t p = ((size_t)b * 512 + chofs + c) * NP + n;
    unsigned k = ((unsigned*)xc)[p];
    float f = funkey(k);
    xc[p] = fmaxf(fmaf(ab[c], f, ab[C + c]), 0.f);
}

// ---- final BN+ReLU + pad channels 512..1023 with zeros ----
__global__ __launch_bounds__(256) void out_kernel(const float* __restrict__ y5,
                                                  const float* __restrict__ ab,
                                                  float* __restrict__ out) {
    size_t t = ((size_t)blockIdx.x * 256 + threadIdx.x) * 4;
    int n  = (int)(t & (NP - 1));
    int bc = (int)(t >> 11);
    int c = bc & 1023;
    int b = bc >> 10;
    float4 v = make_float4(0.f, 0.f, 0.f, 0.f);
    if (c < 512) {
        float a = ab[c], d = ab[512 + c];
        float4 yv = *(const float4*)(y5 + ((size_t)b * 512 + c) * NP + n);
        v.x = fmaxf(fmaf(a, yv.x, d), 0.f);
        v.y = fmaxf(fmaf(a, yv.y, d), 0.f);
        v.z = fmaxf(fmaf(a, yv.z, d), 0.f);
        v.w = fmaxf(fmaf(a, yv.w, d), 0.f);
    }
    *(float4*)(out + t) = v;
}

extern "C" void kernel_launch(void* const* d_in, const int* in_sizes, int n_in,
                              void* d_out, int out_size, void* d_ws, size_t ws_size,
                              hipStream_t stream) {
    (void)in_sizes; (void)n_in; (void)out_size; (void)ws_size;
    const float* x  = (const float*)d_in[0];
    const float* W1 = (const float*)d_in[1];
    const float* W2 = (const float*)d_in[2];
    const float* W3 = (const float*)d_in[3];
    const float* W4 = (const float*)d_in[4];
    const float* W5 = (const float*)d_in[5];
    const float* g1 = (const float*)d_in[6];  const float* b1 = (const float*)d_in[7];
    const float* g2 = (const float*)d_in[8];  const float* b2 = (const float*)d_in[9];
    const float* g3 = (const float*)d_in[10]; const float* b3 = (const float*)d_in[11];
    const float* g4 = (const float*)d_in[12]; const float* b4 = (const float*)d_in[13];
    const float* g5 = (const float*)d_in[14]; const float* b5 = (const float*)d_in[15];

    // ---- workspace layout, ~153 MiB total, lifetime-aliased ----
    char* ws = (char*)d_ws;
    bf16_t* f    = (bf16_t*)(ws + 0);
    bf16_t* y1   = (bf16_t*)(ws + 4194304);
    bf16_t* y3   = (bf16_t*)(ws + 0);
    bf16_t* y2   = (bf16_t*)(ws + 83886080);
    float*  y5   = (float*) (ws + 0);
    float*  xcat = (float*) (ws + 125829120);
    float*  st   = (float*) (ws + 159383552);
    float*  ab   = (float*) (ws + 159391744);
    int*    idx  = (int*)   (ws + 159399936);

    float* st1 = st;        float* ab1 = ab;
    float* st2 = st + 128;  float* ab2 = ab + 128;
    float* st3 = st + 256;  float* ab3 = ab + 256;
    float* st4 = st + 512;  float* ab4 = ab + 512;
    float* st5 = st + 1024; float* ab5 = ab + 1024;

    const float invM14 = 1.f / (float)(BB * SS);   // 1/327680
    const float invM5  = 1.f / (float)(BB * NP);   // 1/16384

    // zero pool keys (xcat) + stats in one pass (contiguous, 2097664 float4s)
    zero_kernel<<<8194, 256, 0, stream>>>(xcat, 2097664);
    knn_kernel<<<1024, 256, 0, stream>>>(x, idx);
    gather_kernel<<<1280, 256, 0, stream>>>(x, idx, f);

    // L1: 6 -> 64 (no input BN)
    conv_tiled<bf16_t, bf16_t, false, true, true><<<dim3(160, 1, 8), 256, 0, stream>>>(
        f, W1, nullptr, y1, (unsigned*)xcat, 0, st1, 6, 64, SS);
    bn_finalize_kernel<<<1, 64, 0, stream>>>(st1, g1, b1, ab1, 64, invM14);
    pool_convert_kernel<<<4096, 256, 0, stream>>>(xcat, ab1, 64, 0);

    // L2: 64 -> 64 (BN1 applied on load)
    conv_tiled<bf16_t, bf16_t, true, true, true><<<dim3(160, 1, 8), 256, 0, stream>>>(
        y1, W2, ab1, y2, (unsigned*)xcat, 64, st2, 64, 64, SS);
    bn_finalize_kernel<<<1, 64, 0, stream>>>(st2, g2, b2, ab2, 64, invM14);
    pool_convert_kernel<<<4096, 256, 0, stream>>>(xcat, ab2, 64, 64);

    // L3: 64 -> 128
    conv_tiled<bf16_t, bf16_t, true, true, true><<<dim3(160, 2, 8), 256, 0, stream>>>(
        y2, W3, ab2, y3, (unsigned*)xcat, 128, st3, 64, 128, SS);
    bn_finalize_kernel<<<2, 64, 0, stream>>>(st3, g3, b3, ab3, 128, invM14);
    pool_convert_kernel<<<8192, 256, 0, stream>>>(xcat, ab3, 128, 128);

    // L4: 128 -> 256, pooled-only (y4 never materialized)
    conv_tiled<bf16_t, float, true, true, false><<<dim3(160, 4, 8), 256, 0, stream>>>(
        y3, W4, ab3, (float*)nullptr, (unsigned*)xcat, 256, st4, 128, 256, SS);
    bn_finalize_kernel<<<4, 64, 0, stream>>>(st4, g4, b4, ab4, 256, invM14);
    pool_convert_kernel<<<16384, 256, 0, stream>>>(xcat, ab4, 256, 256);

    // L5: 512 -> 512 over [B, 512, N] (input already post-BN floats)
    conv_tiled<float, float, false, false, true><<<dim3(8, 8, 8), 256, 0, stream>>>(
        xcat, W5, nullptr, y5, (unsigned*)nullptr, 0, st5, 512, 512, NP);
    bn_finalize_kernel<<<8, 64, 0, stream>>>(st5, g5, b5, ab5, 512, invM5);
    out_kernel<<<16384, 256, 0, stream>>>(y5, ab5, (float*)d_out);
}

// Round 5
// 2674.202 us; speedup vs baseline: 1.0432x; 1.0432x over previous
//
#include <hip/hip_runtime.h>

#define BB  8
#define NP  2048
#define KNB 20
#define SS  (NP * KNB)   // 40960 spatial per batch for layers 1-4

typedef unsigned short bf16_t;

static __device__ __forceinline__ float bf2f(bf16_t u) {
    return __uint_as_float(((unsigned)u) << 16);
}
static __device__ __forceinline__ bf16_t f2bf(float f) {
    unsigned u = __float_as_uint(f);
    return (bf16_t)((u + 0x7fffu + ((u >> 16) & 1u)) >> 16);   // RNE
}

// ---- order-preserving float<->uint for atomicMax pooling ----
static __device__ __forceinline__ unsigned fkey(float f) {
    unsigned u = __float_as_uint(f);
    return (u & 0x80000000u) ? ~u : (u | 0x80000000u);
}
static __device__ __forceinline__ float funkey(unsigned k) {
    return (k & 0x80000000u) ? __uint_as_float(k ^ 0x80000000u) : __uint_as_float(~k);
}

template <typename T> struct V4;
template <> struct V4<float> {
    using t = float4;
    static __device__ __forceinline__ float4 cvt(float4 v) { return v; }
};
template <> struct V4<bf16_t> {
    using t = ushort4;
    static __device__ __forceinline__ float4 cvt(ushort4 v) {
        return make_float4(bf2f(v.x), bf2f(v.y), bf2f(v.z), bf2f(v.w));
    }
};

// ---- zero fill (pool keys + stats, contiguous region) ----
__global__ __launch_bounds__(256) void zero_kernel(float* __restrict__ p, int n4) {
    int t = blockIdx.x * 256 + threadIdx.x;
    if (t < n4) ((float4*)p)[t] = make_float4(0.f, 0.f, 0.f, 0.f);
}

// ==== kNN: 16 points x 16 segments per block, top-20 in explicit scalar
//      registers (no arrays -> no scratch spill), 16-lane shfl merge. ====
#define KDECL(t) float v##t = -3.4e38f; int j##t = 0;
#define KSTEP(t, p) \
    { if (v > v##p) { v##t = v##p; j##t = j##p; } \
      else if (v > v##t) { v##t = v; j##t = j; } }
#define KSHIFT(t, n) v##t = v##n; j##t = j##n;

__global__ __launch_bounds__(256) void knn_kernel(const float* __restrict__ x,
                                                  int* __restrict__ idx) {
    __shared__ float4 tile[2064];    // 2048 + swizzle pad (j + (j>>7)), 33 KB
    const int tid  = threadIdx.x;
    const int b    = blockIdx.x >> 7;     // 128 blocks per batch
    const int pblk = blockIdx.x & 127;
    const int pl   = tid >> 4;            // local point 0..15
    const int seg  = tid & 15;            // segment 0..15 (128 j's each)
    const int i    = pblk * 16 + pl;
    const float* xb = x + (size_t)b * 3 * NP;

    for (int j = tid; j < NP; j += 256) {
        float a0 = xb[j], a1 = xb[NP + j], a2 = xb[2 * NP + j];
        tile[j + (j >> 7)] = make_float4(a0, a1, a2, a0 * a0 + a1 * a1 + a2 * a2);
    }
    __syncthreads();
    const float4 me = tile[i + (i >> 7)];

    KDECL(0)  KDECL(1)  KDECL(2)  KDECL(3)  KDECL(4)
    KDECL(5)  KDECL(6)  KDECL(7)  KDECL(8)  KDECL(9)
    KDECL(10) KDECL(11) KDECL(12) KDECL(13) KDECL(14)
    KDECL(15) KDECL(16) KDECL(17) KDECL(18) KDECL(19)

    const int jbase = seg * 128;
    const float4* tseg = &tile[seg * 129];   // phys base for this segment
    for (int t = 0; t < 128; ++t) {
        float4 p = tseg[t];
        float d = me.x * p.x + me.y * p.y + me.z * p.z;
        float v = 2.0f * d - me.w - p.w;     // same formula as reference
        int j = jbase + t;
        if (v > v19) {
            KSTEP(19,18) KSTEP(18,17) KSTEP(17,16) KSTEP(16,15) KSTEP(15,14)
            KSTEP(14,13) KSTEP(13,12) KSTEP(12,11) KSTEP(11,10) KSTEP(10,9)
            KSTEP(9,8)   KSTEP(8,7)   KSTEP(7,6)   KSTEP(6,5)   KSTEP(5,4)
            KSTEP(4,3)   KSTEP(3,2)   KSTEP(2,1)   KSTEP(1,0)
            if (v > v0) { v0 = v; j0 = j; }
        }
    }

    // merge 16 sorted-desc lists of 20 across the 16 lanes of this point
    int* o = idx + ((size_t)b * NP + i) * KNB;
    float hv = v0; int hj = j0;
    for (int r = 0; r < KNB; ++r) {
        float mv = hv; int mj = hj;
#pragma unroll
        for (int s = 1; s <= 8; s <<= 1) {
            float ov = __shfl_xor(mv, s, 64);
            int   oj = __shfl_xor(mj, s, 64);
            if (ov > mv || (ov == mv && oj < mj)) { mv = ov; mj = oj; }
        }
        if (seg == 0) o[r] = mj;
        if (hv == mv && hj == mj) {          // unique winner pops (j unique)
            KSHIFT(0,1)   KSHIFT(1,2)   KSHIFT(2,3)   KSHIFT(3,4)   KSHIFT(4,5)
            KSHIFT(5,6)   KSHIFT(6,7)   KSHIFT(7,8)   KSHIFT(8,9)   KSHIFT(9,10)
            KSHIFT(10,11) KSHIFT(11,12) KSHIFT(12,13) KSHIFT(13,14) KSHIFT(14,15)
            KSHIFT(15,16) KSHIFT(16,17) KSHIFT(17,18) KSHIFT(18,19)
            v19 = -3.4e38f; j19 = 0;
        }
        hv = v0; hj = j0;
    }
}

// ---- graph feature f[b, 0..5, n*K+k] = [nbr xyz, center xyz], bf16 ----
__global__ __launch_bounds__(256) void gather_kernel(const float* __restrict__ x,
                                                     const int* __restrict__ idx,
                                                     bf16_t* __restrict__ f) {
    int t = blockIdx.x * 256 + threadIdx.x;
    if (t >= BB * SS) return;
    int b = t / SS;
    int r = t - b * SS;
    int n = r / KNB;
    int j = idx[t];
    const float* xb = x + (size_t)b * 3 * NP;
    bf16_t* fb = f + (size_t)b * 6 * SS + r;
    fb[0]          = f2bf(xb[j]);
    fb[SS]         = f2bf(xb[NP + j]);
    fb[2 * SS]     = f2bf(xb[2 * NP + j]);
    fb[3 * SS]     = f2bf(xb[n]);
    fb[4 * SS]     = f2bf(xb[NP + n]);
    fb[5 * SS]     = f2bf(xb[2 * NP + n]);
}

// ==== tiled 1x1 conv. Block: 64 co x 256 s. Thread: 16 co x 4 s. ====
// R4 lesson: acc as a local ARRAY captured by a lambda stayed in scratch
// (VGPR_Count=60 < 64 acc floats; 770us/conv). Explicit float4 registers via
// X-macros (same fix as kNN R3) make spilling impossible.

#define ACC_LIST(M) M(0,A0) M(1,A1) M(2,A2) M(3,A3) M(4,A4) M(5,A5) M(6,A6) M(7,A7) \
    M(8,A8) M(9,A9) M(10,A10) M(11,A11) M(12,A12) M(13,A13) M(14,A14) M(15,A15)

#define ACC_DECL(r, A) float4 A = make_float4(0.f, 0.f, 0.f, 0.f);

#define FMA4(A, W) { A.x = fmaf(W, hv.x, A.x); A.y = fmaf(W, hv.y, A.y); \
                     A.z = fmaf(W, hv.z, A.z); A.w = fmaf(W, hv.w, A.w); }

#define CONV_BODY(cc) { \
    typename V4<TIN>::t raw = *(const typename V4<TIN>::t*)(h + (size_t)(c0 + (cc)) * Ssz); \
    float4 hv = V4<TIN>::cvt(raw); \
    if constexpr (INBN) { \
        float a_ = abin[c0 + (cc)], d_ = abin[Cin + c0 + (cc)]; \
        hv.x = fmaxf(fmaf(a_, hv.x, d_), 0.f); \
        hv.y = fmaxf(fmaf(a_, hv.y, d_), 0.f); \
        hv.z = fmaxf(fmaf(a_, hv.z, d_), 0.f); \
        hv.w = fmaxf(fmaf(a_, hv.w, d_), 0.f); \
    } \
    const float4* wp = (const float4*)(&wl[(cc)][cs << 4]); \
    float4 w_; \
    w_ = wp[0]; FMA4(A0,  w_.x) FMA4(A1,  w_.y) FMA4(A2,  w_.z) FMA4(A3,  w_.w) \
    w_ = wp[1]; FMA4(A4,  w_.x) FMA4(A5,  w_.y) FMA4(A6,  w_.z) FMA4(A7,  w_.w) \
    w_ = wp[2]; FMA4(A8,  w_.x) FMA4(A9,  w_.y) FMA4(A10, w_.z) FMA4(A11, w_.w) \
    w_ = wp[3]; FMA4(A12, w_.x) FMA4(A13, w_.y) FMA4(A14, w_.z) FMA4(A15, w_.w) \
}

#define STORE1(r, A) { \
    if constexpr (sizeof(TOUT) == 2) { \
        ushort4 o_; o_.x = f2bf(A.x); o_.y = f2bf(A.y); o_.z = f2bf(A.z); o_.w = f2bf(A.w); \
        *(ushort4*)((bf16_t*)y + (size_t)(r) * Ssz) = o_; \
    } else { \
        *(float4*)((float*)y + (size_t)(r) * Ssz) = A; \
    } }

#define POOL1(r, A) { \
    float m_ = fmaxf(fmaxf(A.x, A.y), fmaxf(A.z, A.w)); \
    float t_; \
    t_ = __shfl_down(m_, 1, 64); if (ok1) m_ = fmaxf(m_, t_); \
    t_ = __shfl_down(m_, 2, 64); if (ok2) m_ = fmaxf(m_, t_); \
    t_ = __shfl_down(m_, 4, 64); if (ok4) m_ = fmaxf(m_, t_); \
    if (leader) atomicMax(Mp + (size_t)(r) * NP, fkey(m_)); }

#define STATS1(r, A) { \
    float sv = A.x + A.y + A.z + A.w; \
    float qv = A.x * A.x + A.y * A.y + A.z * A.z + A.w * A.w; \
    sv += __shfl_xor(sv, 1, 64);  qv += __shfl_xor(qv, 1, 64); \
    sv += __shfl_xor(sv, 2, 64);  qv += __shfl_xor(qv, 2, 64); \
    sv += __shfl_xor(sv, 4, 64);  qv += __shfl_xor(qv, 4, 64); \
    sv += __shfl_xor(sv, 8, 64);  qv += __shfl_xor(qv, 8, 64); \
    sv += __shfl_xor(sv, 16, 64); qv += __shfl_xor(qv, 16, 64); \
    sv += __shfl_xor(sv, 32, 64); qv += __shfl_xor(qv, 32, 64); \
    if (sx == 0) { \
        atomicAdd(&stats[cob + (cs << 4) + (r)], sv); \
        atomicAdd(&stats[Cout + cob + (cs << 4) + (r)], qv); \
    } }

template <typename TIN, typename TOUT, bool INBN, bool POOL, bool STORE>
__global__ __launch_bounds__(256, 2) void conv_tiled(
    const TIN* __restrict__ H, const float* __restrict__ Wt,
    const float* __restrict__ abin,
    TOUT* __restrict__ Y, unsigned* __restrict__ Mx, int chofs,
    float* __restrict__ stats, int Cin, int Cout, int Ssz) {
    __shared__ __align__(16) float wl[16][64];
    const int tid = threadIdx.x;
    const int sx  = tid & 63;        // lane (wave == co-subtile: cs uniform/wave)
    const int cs  = tid >> 6;
    const int s0  = blockIdx.x * 256 + sx * 4;
    const int cob = blockIdx.y * 64;
    const int b   = blockIdx.z;

    const TIN* h = H + (size_t)b * Cin * Ssz + s0;

    ACC_LIST(ACC_DECL)

    int c0 = 0;
    for (; c0 + 16 <= Cin; c0 += 16) {
        __syncthreads();
        for (int e = tid; e < 1024; e += 256) {
            int cc = e >> 6, co = e & 63;
            wl[cc][co] = Wt[(size_t)(cob + co) * Cin + (c0 + cc)];
        }
        __syncthreads();
#pragma unroll
        for (int cc = 0; cc < 16; ++cc) CONV_BODY(cc)
    }
    if (c0 < Cin) {
        const int chunk = Cin - c0;
        __syncthreads();
        for (int e = tid; e < (chunk << 6); e += 256) {
            int cc = e >> 6, co = e & 63;
            wl[cc][co] = Wt[(size_t)(cob + co) * Cin + (c0 + cc)];
        }
        __syncthreads();
        for (int cc = 0; cc < chunk; ++cc) CONV_BODY(cc)
    }

    if constexpr (STORE) {
        TOUT* y = Y + ((size_t)b * Cout + cob + (cs << 4)) * Ssz + s0;
        ACC_LIST(STORE1)
    }

    if constexpr (POOL) {
        const int n = s0 / KNB;           // 4 cols of a thread share one n
        int pn = __shfl_up(n, 1, 64);
        bool leader = (sx == 0) || (pn != n);
        bool ok1 = (__shfl_down(n, 1, 64) == n) && (sx + 1 < 64);
        bool ok2 = (__shfl_down(n, 2, 64) == n) && (sx + 2 < 64);
        bool ok4 = (__shfl_down(n, 4, 64) == n) && (sx + 4 < 64);
        unsigned* Mp = &Mx[((size_t)b * 512 + chofs + cob + (cs << 4)) * NP + n];
        ACC_LIST(POOL1)
    }

    // BN stats: wave reduce (wave == one 16-co subtile), then atomicAdd
    ACC_LIST(STATS1)
}

// ---- stats -> affine coefs: a = g*rsqrt(var+eps), d = b - mean*a ----
__global__ void bn_finalize_kernel(const float* __restrict__ stats,
                                   const float* __restrict__ g,
                                   const float* __restrict__ bt,
                                   float* __restrict__ ab, int C, float invM) {
    int c = blockIdx.x * 64 + threadIdx.x;
    if (c >= C) return;
    float mean = stats[c] * invM;
    float var  = fmaxf(stats[C + c] * invM - mean * mean, 0.f);
    float a = g[c] * rsqrtf(var + 1e-5f);
    ab[c] = a;
    ab[C + c] = fmaf(-mean, a, bt[c]);
}

// ---- decode pooled-max key, apply BN+ReLU, write float into xcat ----
__global__ __launch_bounds__(256) void pool_convert_kernel(float* __restrict__ xc,
                                                           const float* __restrict__ ab,
                                                           int C, int chofs) {
    int t = blockIdx.x * 256 + threadIdx.x;   // exact grid over B*C*NP
    int n = t & (NP - 1);
    int bc = t >> 11;
    int c = bc % C;
    int b = bc / C;
    size_t p = ((size_t)b * 512 + chofs + c) * NP + n;
    unsigned k = ((unsigned*)xc)[p];
    float f = funkey(k);
    xc[p] = fmaxf(fmaf(ab[c], f, ab[C + c]), 0.f);
}

// ---- final BN+ReLU + pad channels 512..1023 with zeros ----
__global__ __launch_bounds__(256) void out_kernel(const float* __restrict__ y5,
                                                  const float* __restrict__ ab,
                                                  float* __restrict__ out) {
    size_t t = ((size_t)blockIdx.x * 256 + threadIdx.x) * 4;
    int n  = (int)(t & (NP - 1));
    int bc = (int)(t >> 11);
    int c = bc & 1023;
    int b = bc >> 10;
    float4 v = make_float4(0.f, 0.f, 0.f, 0.f);
    if (c < 512) {
        float a = ab[c], d = ab[512 + c];
        float4 yv = *(const float4*)(y5 + ((size_t)b * 512 + c) * NP + n);
        v.x = fmaxf(fmaf(a, yv.x, d), 0.f);
        v.y = fmaxf(fmaf(a, yv.y, d), 0.f);
        v.z = fmaxf(fmaf(a, yv.z, d), 0.f);
        v.w = fmaxf(fmaf(a, yv.w, d), 0.f);
    }
    *(float4*)(out + t) = v;
}

extern "C" void kernel_launch(void* const* d_in, const int* in_sizes, int n_in,
                              void* d_out, int out_size, void* d_ws, size_t ws_size,
                              hipStream_t stream) {
    (void)in_sizes; (void)n_in; (void)out_size; (void)ws_size;
    const float* x  = (const float*)d_in[0];
    const float* W1 = (const float*)d_in[1];
    const float* W2 = (const float*)d_in[2];
    const float* W3 = (const float*)d_in[3];
    const float* W4 = (const float*)d_in[4];
    const float* W5 = (const float*)d_in[5];
    const float* g1 = (const float*)d_in[6];  const float* b1 = (const float*)d_in[7];
    const float* g2 = (const float*)d_in[8];  const float* b2 = (const float*)d_in[9];
    const float* g3 = (const float*)d_in[10]; const float* b3 = (const float*)d_in[11];
    const float* g4 = (const float*)d_in[12]; const float* b4 = (const float*)d_in[13];
    const float* g5 = (const float*)d_in[14]; const float* b5 = (const float*)d_in[15];

    // ---- workspace layout, ~153 MiB total, lifetime-aliased ----
    char* ws = (char*)d_ws;
    bf16_t* f    = (bf16_t*)(ws + 0);
    bf16_t* y1   = (bf16_t*)(ws + 4194304);
    bf16_t* y3   = (bf16_t*)(ws + 0);
    bf16_t* y2   = (bf16_t*)(ws + 83886080);
    float*  y5   = (float*) (ws + 0);
    float*  xcat = (float*) (ws + 125829120);
    float*  st   = (float*) (ws + 159383552);
    float*  ab   = (float*) (ws + 159391744);
    int*    idx  = (int*)   (ws + 159399936);

    float* st1 = st;        float* ab1 = ab;
    float* st2 = st + 128;  float* ab2 = ab + 128;
    float* st3 = st + 256;  float* ab3 = ab + 256;
    float* st4 = st + 512;  float* ab4 = ab + 512;
    float* st5 = st + 1024; float* ab5 = ab + 1024;

    const float invM14 = 1.f / (float)(BB * SS);   // 1/327680
    const float invM5  = 1.f / (float)(BB * NP);   // 1/16384

    // zero pool keys (xcat) + stats in one pass (contiguous, 2097664 float4s)
    zero_kernel<<<8194, 256, 0, stream>>>(xcat, 2097664);
    knn_kernel<<<1024, 256, 0, stream>>>(x, idx);
    gather_kernel<<<1280, 256, 0, stream>>>(x, idx, f);

    // L1: 6 -> 64 (no input BN)
    conv_tiled<bf16_t, bf16_t, false, true, true><<<dim3(160, 1, 8), 256, 0, stream>>>(
        f, W1, nullptr, y1, (unsigned*)xcat, 0, st1, 6, 64, SS);
    bn_finalize_kernel<<<1, 64, 0, stream>>>(st1, g1, b1, ab1, 64, invM14);
    pool_convert_kernel<<<4096, 256, 0, stream>>>(xcat, ab1, 64, 0);

    // L2: 64 -> 64 (BN1 applied on load)
    conv_tiled<bf16_t, bf16_t, true, true, true><<<dim3(160, 1, 8), 256, 0, stream>>>(
        y1, W2, ab1, y2, (unsigned*)xcat, 64, st2, 64, 64, SS);
    bn_finalize_kernel<<<1, 64, 0, stream>>>(st2, g2, b2, ab2, 64, invM14);
    pool_convert_kernel<<<4096, 256, 0, stream>>>(xcat, ab2, 64, 64);

    // L3: 64 -> 128
    conv_tiled<bf16_t, bf16_t, true, true, true><<<dim3(160, 2, 8), 256, 0, stream>>>(
        y2, W3, ab2, y3, (unsigned*)xcat, 128, st3, 64, 128, SS);
    bn_finalize_kernel<<<2, 64, 0, stream>>>(st3, g3, b3, ab3, 128, invM14);
    pool_convert_kernel<<<8192, 256, 0, stream>>>(xcat, ab3, 128, 128);

    // L4: 128 -> 256, pooled-only (y4 never materialized)
    conv_tiled<bf16_t, float, true, true, false><<<dim3(160, 4, 8), 256, 0, stream>>>(
        y3, W4, ab3, (float*)nullptr, (unsigned*)xcat, 256, st4, 128, 256, SS);
    bn_finalize_kernel<<<4, 64, 0, stream>>>(st4, g4, b4, ab4, 256, invM14);
    pool_convert_kernel<<<16384, 256, 0, stream>>>(xcat, ab4, 256, 256);

    // L5: 512 -> 512 over [B, 512, N] (input already post-BN floats)
    conv_tiled<float, float, false, false, true><<<dim3(8, 8, 8), 256, 0, stream>>>(
        xcat, W5, nullptr, y5, (unsigned*)nullptr, 0, st5, 512, 512, NP);
    bn_finalize_kernel<<<8, 64, 0, stream>>>(st5, g5, b5, ab5, 512, invM5);
    out_kernel<<<16384, 256, 0, stream>>>(y5, ab5, (float*)d_out);
}

// Round 6
// 2635.492 us; speedup vs baseline: 1.0585x; 1.0147x over previous
//
#include <hip/hip_runtime.h>

#define BB  8
#define NP  2048
#define KNB 20
#define SS  (NP * KNB)   // 40960 spatial per batch for layers 1-4

typedef unsigned short bf16_t;

static __device__ __forceinline__ float bf2f(bf16_t u) {
    return __uint_as_float(((unsigned)u) << 16);
}
static __device__ __forceinline__ bf16_t f2bf(float f) {
    unsigned u = __float_as_uint(f);
    return (bf16_t)((u + 0x7fffu + ((u >> 16) & 1u)) >> 16);   // RNE
}

// ---- order-preserving float<->uint for atomicMax pooling ----
static __device__ __forceinline__ unsigned fkey(float f) {
    unsigned u = __float_as_uint(f);
    return (u & 0x80000000u) ? ~u : (u | 0x80000000u);
}
static __device__ __forceinline__ float funkey(unsigned k) {
    return (k & 0x80000000u) ? __uint_as_float(k ^ 0x80000000u) : __uint_as_float(~k);
}

template <typename T> struct V4;
template <> struct V4<float> {
    using t = float4;
    static __device__ __forceinline__ float4 cvt(float4 v) { return v; }
};
template <> struct V4<bf16_t> {
    using t = ushort4;
    static __device__ __forceinline__ float4 cvt(ushort4 v) {
        return make_float4(bf2f(v.x), bf2f(v.y), bf2f(v.z), bf2f(v.w));
    }
};

// ---- zero fill (pool keys + stats, contiguous region) ----
__global__ __launch_bounds__(256) void zero_kernel(float* __restrict__ p, int n4) {
    int t = blockIdx.x * 256 + threadIdx.x;
    if (t < n4) ((float4*)p)[t] = make_float4(0.f, 0.f, 0.f, 0.f);
}

// ==== kNN: 16 points x 16 segments per block, top-20 in explicit scalar
//      registers (no arrays -> no scratch spill), 16-lane shfl merge. ====
#define KDECL(t) float v##t = -3.4e38f; int j##t = 0;
#define KSTEP(t, p) \
    { if (v > v##p) { v##t = v##p; j##t = j##p; } \
      else if (v > v##t) { v##t = v; j##t = j; } }
#define KSHIFT(t, n) v##t = v##n; j##t = j##n;

__global__ __launch_bounds__(256) void knn_kernel(const float* __restrict__ x,
                                                  int* __restrict__ idx) {
    __shared__ float4 tile[2064];    // 2048 + swizzle pad (j + (j>>7)), 33 KB
    const int tid  = threadIdx.x;
    const int b    = blockIdx.x >> 7;     // 128 blocks per batch
    const int pblk = blockIdx.x & 127;
    const int pl   = tid >> 4;            // local point 0..15
    const int seg  = tid & 15;            // segment 0..15 (128 j's each)
    const int i    = pblk * 16 + pl;
    const float* xb = x + (size_t)b * 3 * NP;

    for (int j = tid; j < NP; j += 256) {
        float a0 = xb[j], a1 = xb[NP + j], a2 = xb[2 * NP + j];
        tile[j + (j >> 7)] = make_float4(a0, a1, a2, a0 * a0 + a1 * a1 + a2 * a2);
    }
    __syncthreads();
    const float4 me = tile[i + (i >> 7)];

    KDECL(0)  KDECL(1)  KDECL(2)  KDECL(3)  KDECL(4)
    KDECL(5)  KDECL(6)  KDECL(7)  KDECL(8)  KDECL(9)
    KDECL(10) KDECL(11) KDECL(12) KDECL(13) KDECL(14)
    KDECL(15) KDECL(16) KDECL(17) KDECL(18) KDECL(19)

    const int jbase = seg * 128;
    const float4* tseg = &tile[seg * 129];   // phys base for this segment
    for (int t = 0; t < 128; ++t) {
        float4 p = tseg[t];
        float d = me.x * p.x + me.y * p.y + me.z * p.z;
        float v = 2.0f * d - me.w - p.w;     // same formula as reference
        int j = jbase + t;
        if (v > v19) {
            KSTEP(19,18) KSTEP(18,17) KSTEP(17,16) KSTEP(16,15) KSTEP(15,14)
            KSTEP(14,13) KSTEP(13,12) KSTEP(12,11) KSTEP(11,10) KSTEP(10,9)
            KSTEP(9,8)   KSTEP(8,7)   KSTEP(7,6)   KSTEP(6,5)   KSTEP(5,4)
            KSTEP(4,3)   KSTEP(3,2)   KSTEP(2,1)   KSTEP(1,0)
            if (v > v0) { v0 = v; j0 = j; }
        }
    }

    // merge 16 sorted-desc lists of 20 across the 16 lanes of this point
    int* o = idx + ((size_t)b * NP + i) * KNB;
    float hv = v0; int hj = j0;
    for (int r = 0; r < KNB; ++r) {
        float mv = hv; int mj = hj;
#pragma unroll
        for (int s = 1; s <= 8; s <<= 1) {
            float ov = __shfl_xor(mv, s, 64);
            int   oj = __shfl_xor(mj, s, 64);
            if (ov > mv || (ov == mv && oj < mj)) { mv = ov; mj = oj; }
        }
        if (seg == 0) o[r] = mj;
        if (hv == mv && hj == mj) {          // unique winner pops (j unique)
            KSHIFT(0,1)   KSHIFT(1,2)   KSHIFT(2,3)   KSHIFT(3,4)   KSHIFT(4,5)
            KSHIFT(5,6)   KSHIFT(6,7)   KSHIFT(7,8)   KSHIFT(8,9)   KSHIFT(9,10)
            KSHIFT(10,11) KSHIFT(11,12) KSHIFT(12,13) KSHIFT(13,14) KSHIFT(14,15)
            KSHIFT(15,16) KSHIFT(16,17) KSHIFT(17,18) KSHIFT(18,19)
            v19 = -3.4e38f; j19 = 0;
        }
        hv = v0; hj = j0;
    }
}

// ---- graph feature f[b, 0..5, n*K+k] = [nbr xyz, center xyz], bf16 ----
__global__ __launch_bounds__(256) void gather_kernel(const float* __restrict__ x,
                                                     const int* __restrict__ idx,
                                                     bf16_t* __restrict__ f) {
    int t = blockIdx.x * 256 + threadIdx.x;
    if (t >= BB * SS) return;
    int b = t / SS;
    int r = t - b * SS;
    int n = r / KNB;
    int j = idx[t];
    const float* xb = x + (size_t)b * 3 * NP;
    bf16_t* fb = f + (size_t)b * 6 * SS + r;
    fb[0]          = f2bf(xb[j]);
    fb[SS]         = f2bf(xb[NP + j]);
    fb[2 * SS]     = f2bf(xb[2 * NP + j]);
    fb[3 * SS]     = f2bf(xb[n]);
    fb[4 * SS]     = f2bf(xb[NP + n]);
    fb[5 * SS]     = f2bf(xb[2 * NP + n]);
}

// ==== tiled 1x1 conv. Block: 32 co x 256 s. Thread: 8 co x 4 s. ====
// R5 lesson: the allocator pins VGPRs at ~64 regardless of launch_bounds, so
// a 64-float acc tile ALWAYS spills to scratch (~715us/conv, 40x slow). Fix:
// 32-float acc tile (8 co) fits the 64-VGPR budget -> spill impossible; plus
// amdgpu_waves_per_eu(2,8) to request a larger budget directly.

#define ACC_LIST(M) M(0,A0) M(1,A1) M(2,A2) M(3,A3) M(4,A4) M(5,A5) M(6,A6) M(7,A7)

#define ACC_DECL(r, A) float4 A = make_float4(0.f, 0.f, 0.f, 0.f);

#define FMA4(A, W) { A.x = fmaf(W, hv.x, A.x); A.y = fmaf(W, hv.y, A.y); \
                     A.z = fmaf(W, hv.z, A.z); A.w = fmaf(W, hv.w, A.w); }

#define CONV_BODY(cc) { \
    typename V4<TIN>::t raw = *(const typename V4<TIN>::t*)(h + (size_t)(c0 + (cc)) * Ssz); \
    float4 hv = V4<TIN>::cvt(raw); \
    if constexpr (INBN) { \
        float a_ = abin[c0 + (cc)], d_ = abin[Cin + c0 + (cc)]; \
        hv.x = fmaxf(fmaf(a_, hv.x, d_), 0.f); \
        hv.y = fmaxf(fmaf(a_, hv.y, d_), 0.f); \
        hv.z = fmaxf(fmaf(a_, hv.z, d_), 0.f); \
        hv.w = fmaxf(fmaf(a_, hv.w, d_), 0.f); \
    } \
    const float4* wp = (const float4*)(&wl[(cc)][cs << 3]); \
    float4 w_; \
    w_ = wp[0]; FMA4(A0, w_.x) FMA4(A1, w_.y) FMA4(A2, w_.z) FMA4(A3, w_.w) \
    w_ = wp[1]; FMA4(A4, w_.x) FMA4(A5, w_.y) FMA4(A6, w_.z) FMA4(A7, w_.w) \
}

#define STORE1(r, A) { \
    if constexpr (sizeof(TOUT) == 2) { \
        ushort4 o_; o_.x = f2bf(A.x); o_.y = f2bf(A.y); o_.z = f2bf(A.z); o_.w = f2bf(A.w); \
        *(ushort4*)((bf16_t*)y + (size_t)(r) * Ssz) = o_; \
    } else { \
        *(float4*)((float*)y + (size_t)(r) * Ssz) = A; \
    } }

#define POOL1(r, A) { \
    float m_ = fmaxf(fmaxf(A.x, A.y), fmaxf(A.z, A.w)); \
    float t_; \
    t_ = __shfl_down(m_, 1, 64); if (ok1) m_ = fmaxf(m_, t_); \
    t_ = __shfl_down(m_, 2, 64); if (ok2) m_ = fmaxf(m_, t_); \
    t_ = __shfl_down(m_, 4, 64); if (ok4) m_ = fmaxf(m_, t_); \
    if (leader) atomicMax(Mp + (size_t)(r) * NP, fkey(m_)); }

#define STATS1(r, A) { \
    float sv = A.x + A.y + A.z + A.w; \
    float qv = A.x * A.x + A.y * A.y + A.z * A.z + A.w * A.w; \
    sv += __shfl_xor(sv, 1, 64);  qv += __shfl_xor(qv, 1, 64); \
    sv += __shfl_xor(sv, 2, 64);  qv += __shfl_xor(qv, 2, 64); \
    sv += __shfl_xor(sv, 4, 64);  qv += __shfl_xor(qv, 4, 64); \
    sv += __shfl_xor(sv, 8, 64);  qv += __shfl_xor(qv, 8, 64); \
    sv += __shfl_xor(sv, 16, 64); qv += __shfl_xor(qv, 16, 64); \
    sv += __shfl_xor(sv, 32, 64); qv += __shfl_xor(qv, 32, 64); \
    if (sx == 0) { \
        atomicAdd(&stats[cob + (cs << 3) + (r)], sv); \
        atomicAdd(&stats[Cout + cob + (cs << 3) + (r)], qv); \
    } }

template <typename TIN, typename TOUT, bool INBN, bool POOL, bool STORE>
__global__ __launch_bounds__(256)
__attribute__((amdgpu_waves_per_eu(2, 8)))
void conv_tiled(
    const TIN* __restrict__ H, const float* __restrict__ Wt,
    const float* __restrict__ abin,
    TOUT* __restrict__ Y, unsigned* __restrict__ Mx, int chofs,
    float* __restrict__ stats, int Cin, int Cout, int Ssz) {
    __shared__ __align__(16) float wl[16][32];
    const int tid = threadIdx.x;
    const int sx  = tid & 63;        // lane (wave == co-subtile: cs uniform/wave)
    const int cs  = tid >> 6;        // wave id -> 8-co subtile
    const int s0  = blockIdx.x * 256 + sx * 4;
    const int cob = blockIdx.y * 32;
    const int b   = blockIdx.z;

    const TIN* h = H + (size_t)b * Cin * Ssz + s0;

    ACC_LIST(ACC_DECL)

    int c0 = 0;
    for (; c0 + 16 <= Cin; c0 += 16) {
        __syncthreads();
        for (int e = tid; e < 512; e += 256) {
            int cc = e >> 5, co = e & 31;
            wl[cc][co] = Wt[(size_t)(cob + co) * Cin + (c0 + cc)];
        }
        __syncthreads();
#pragma unroll
        for (int cc = 0; cc < 16; ++cc) CONV_BODY(cc)
    }
    if (c0 < Cin) {
        const int chunk = Cin - c0;
        __syncthreads();
        for (int e = tid; e < (chunk << 5); e += 256) {
            int cc = e >> 5, co = e & 31;
            wl[cc][co] = Wt[(size_t)(cob + co) * Cin + (c0 + cc)];
        }
        __syncthreads();
        for (int cc = 0; cc < chunk; ++cc) CONV_BODY(cc)
    }

    if constexpr (STORE) {
        TOUT* y = Y + ((size_t)b * Cout + cob + (cs << 3)) * Ssz + s0;
        ACC_LIST(STORE1)
    }

    if constexpr (POOL) {
        const int n = s0 / KNB;           // 4 cols of a thread share one n
        int pn = __shfl_up(n, 1, 64);
        bool leader = (sx == 0) || (pn != n);
        bool ok1 = (__shfl_down(n, 1, 64) == n) && (sx + 1 < 64);
        bool ok2 = (__shfl_down(n, 2, 64) == n) && (sx + 2 < 64);
        bool ok4 = (__shfl_down(n, 4, 64) == n) && (sx + 4 < 64);
        unsigned* Mp = &Mx[((size_t)b * 512 + chofs + cob + (cs << 3)) * NP + n];
        ACC_LIST(POOL1)
    }

    // BN stats: wave reduce (wave == one 8-co subtile), then atomicAdd
    ACC_LIST(STATS1)
}

// ---- stats -> affine coefs: a = g*rsqrt(var+eps), d = b - mean*a ----
__global__ void bn_finalize_kernel(const float* __restrict__ stats,
                                   const float* __restrict__ g,
                                   const float* __restrict__ bt,
                                   float* __restrict__ ab, int C, float invM) {
    int c = blockIdx.x * 64 + threadIdx.x;
    if (c >= C) return;
    float mean = stats[c] * invM;
    float var  = fmaxf(stats[C + c] * invM - mean * mean, 0.f);
    float a = g[c] * rsqrtf(var + 1e-5f);
    ab[c] = a;
    ab[C + c] = fmaf(-mean, a, bt[c]);
}

// ---- decode pooled-max key, apply BN+ReLU, write float into xcat ----
__global__ __launch_bounds__(256) void pool_convert_kernel(float* __restrict__ xc,
                                                           const float* __restrict__ ab,
                                                           int C, int chofs) {
    int t = blockIdx.x * 256 + threadIdx.x;   // exact grid over B*C*NP
    int n = t & (NP - 1);
    int bc = t >> 11;
    int c = bc % C;
    int b = bc / C;
    size_t p = ((size_t)b * 512 + chofs + c) * NP + n;
    unsigned k = ((unsigned*)xc)[p];
    float f = funkey(k);
    xc[p] = fmaxf(fmaf(ab[c], f, ab[C + c]), 0.f);
}

// ---- final BN+ReLU + pad channels 512..1023 with zeros ----
__global__ __launch_bounds__(256) void out_kernel(const float* __restrict__ y5,
                                                  const float* __restrict__ ab,
                                                  float* __restrict__ out) {
    size_t t = ((size_t)blockIdx.x * 256 + threadIdx.x) * 4;
    int n  = (int)(t & (NP - 1));
    int bc = (int)(t >> 11);
    int c = bc & 1023;
    int b = bc >> 10;
    float4 v = make_float4(0.f, 0.f, 0.f, 0.f);
    if (c < 512) {
        float a = ab[c], d = ab[512 + c];
        float4 yv = *(const float4*)(y5 + ((size_t)b * 512 + c) * NP + n);
        v.x = fmaxf(fmaf(a, yv.x, d), 0.f);
        v.y = fmaxf(fmaf(a, yv.y, d), 0.f);
        v.z = fmaxf(fmaf(a, yv.z, d), 0.f);
        v.w = fmaxf(fmaf(a, yv.w, d), 0.f);
    }
    *(float4*)(out + t) = v;
}

extern "C" void kernel_launch(void* const* d_in, const int* in_sizes, int n_in,
                              void* d_out, int out_size, void* d_ws, size_t ws_size,
                              hipStream_t stream) {
    (void)in_sizes; (void)n_in; (void)out_size; (void)ws_size;
    const float* x  = (const float*)d_in[0];
    const float* W1 = (const float*)d_in[1];
    const float* W2 = (const float*)d_in[2];
    const float* W3 = (const float*)d_in[3];
    const float* W4 = (const float*)d_in[4];
    const float* W5 = (const float*)d_in[5];
    const float* g1 = (const float*)d_in[6];  const float* b1 = (const float*)d_in[7];
    const float* g2 = (const float*)d_in[8];  const float* b2 = (const float*)d_in[9];
    const float* g3 = (const float*)d_in[10]; const float* b3 = (const float*)d_in[11];
    const float* g4 = (const float*)d_in[12]; const float* b4 = (const float*)d_in[13];
    const float* g5 = (const float*)d_in[14]; const float* b5 = (const float*)d_in[15];

    // ---- workspace layout, ~153 MiB total, lifetime-aliased ----
    char* ws = (char*)d_ws;
    bf16_t* f    = (bf16_t*)(ws + 0);
    bf16_t* y1   = (bf16_t*)(ws + 4194304);
    bf16_t* y3   = (bf16_t*)(ws + 0);
    bf16_t* y2   = (bf16_t*)(ws + 83886080);
    float*  y5   = (float*) (ws + 0);
    float*  xcat = (float*) (ws + 125829120);
    float*  st   = (float*) (ws + 159383552);
    float*  ab   = (float*) (ws + 159391744);
    int*    idx  = (int*)   (ws + 159399936);

    float* st1 = st;        float* ab1 = ab;
    float* st2 = st + 128;  float* ab2 = ab + 128;
    float* st3 = st + 256;  float* ab3 = ab + 256;
    float* st4 = st + 512;  float* ab4 = ab + 512;
    float* st5 = st + 1024; float* ab5 = ab + 1024;

    const float invM14 = 1.f / (float)(BB * SS);   // 1/327680
    const float invM5  = 1.f / (float)(BB * NP);   // 1/16384

    // zero pool keys (xcat) + stats in one pass (contiguous, 2097664 float4s)
    zero_kernel<<<8194, 256, 0, stream>>>(xcat, 2097664);
    knn_kernel<<<1024, 256, 0, stream>>>(x, idx);
    gather_kernel<<<1280, 256, 0, stream>>>(x, idx, f);

    // L1: 6 -> 64 (no input BN)
    conv_tiled<bf16_t, bf16_t, false, true, true><<<dim3(160, 2, 8), 256, 0, stream>>>(
        f, W1, nullptr, y1, (unsigned*)xcat, 0, st1, 6, 64, SS);
    bn_finalize_kernel<<<1, 64, 0, stream>>>(st1, g1, b1, ab1, 64, invM14);
    pool_convert_kernel<<<4096, 256, 0, stream>>>(xcat, ab1, 64, 0);

    // L2: 64 -> 64 (BN1 applied on load)
    conv_tiled<bf16_t, bf16_t, true, true, true><<<dim3(160, 2, 8), 256, 0, stream>>>(
        y1, W2, ab1, y2, (unsigned*)xcat, 64, st2, 64, 64, SS);
    bn_finalize_kernel<<<1, 64, 0, stream>>>(st2, g2, b2, ab2, 64, invM14);
    pool_convert_kernel<<<4096, 256, 0, stream>>>(xcat, ab2, 64, 64);

    // L3: 64 -> 128
    conv_tiled<bf16_t, bf16_t, true, true, true><<<dim3(160, 4, 8), 256, 0, stream>>>(
        y2, W3, ab2, y3, (unsigned*)xcat, 128, st3, 64, 128, SS);
    bn_finalize_kernel<<<2, 64, 0, stream>>>(st3, g3, b3, ab3, 128, invM14);
    pool_convert_kernel<<<8192, 256, 0, stream>>>(xcat, ab3, 128, 128);

    // L4: 128 -> 256, pooled-only (y4 never materialized)
    conv_tiled<bf16_t, float, true, true, false><<<dim3(160, 8, 8), 256, 0, stream>>>(
        y3, W4, ab3, (float*)nullptr, (unsigned*)xcat, 256, st4, 128, 256, SS);
    bn_finalize_kernel<<<4, 64, 0, stream>>>(st4, g4, b4, ab4, 256, invM14);
    pool_convert_kernel<<<16384, 256, 0, stream>>>(xcat, ab4, 256, 256);

    // L5: 512 -> 512 over [B, 512, N] (input already post-BN floats)
    conv_tiled<float, float, false, false, true><<<dim3(8, 16, 8), 256, 0, stream>>>(
        xcat, W5, nullptr, y5, (unsigned*)nullptr, 0, st5, 512, 512, NP);
    bn_finalize_kernel<<<8, 64, 0, stream>>>(st5, g5, b5, ab5, 512, invM5);
    out_kernel<<<16384, 256, 0, stream>>>(y5, ab5, (float*)d_out);
}

// Round 8
// 1137.759 us; speedup vs baseline: 2.4519x; 2.3164x over previous
//
#include <hip/hip_runtime.h>

#define BB  8
#define NP  2048
#define KNB 20
#define SS  40960   // spatial per batch, layers 1-4

typedef unsigned short bf16_t;
typedef __attribute__((ext_vector_type(8))) short short8_t;   // MFMA A/B frag (8 bf16)
typedef __attribute__((ext_vector_type(4))) float f32x4;      // MFMA C/D frag

static __device__ __forceinline__ float bf2f(unsigned short u) {
    return __uint_as_float(((unsigned)u) << 16);
}
static __device__ __forceinline__ bf16_t f2bf(float f) {
    unsigned u = __float_as_uint(f);
    return (bf16_t)((u + 0x7fffu + ((u >> 16) & 1u)) >> 16);   // RNE
}

// ==== kNN (unchanged: register top-20, 16x16 shfl merge; passed R3-R6) ====
#define KDECL(t) float v##t = -3.4e38f; int j##t = 0;
#define KSTEP(t, p) \
    { if (v > v##p) { v##t = v##p; j##t = j##p; } \
      else if (v > v##t) { v##t = v; j##t = j; } }
#define KSHIFT(t, n) v##t = v##n; j##t = j##n;

__global__ __launch_bounds__(256) void knn_kernel(const float* __restrict__ x,
                                                  int* __restrict__ idx) {
    __shared__ float4 tile[2064];
    const int tid  = threadIdx.x;
    const int b    = blockIdx.x >> 7;
    const int pblk = blockIdx.x & 127;
    const int pl   = tid >> 4;
    const int seg  = tid & 15;
    const int i    = pblk * 16 + pl;
    const float* xb = x + (size_t)b * 3 * NP;

    for (int j = tid; j < NP; j += 256) {
        float a0 = xb[j], a1 = xb[NP + j], a2 = xb[2 * NP + j];
        tile[j + (j >> 7)] = make_float4(a0, a1, a2, a0 * a0 + a1 * a1 + a2 * a2);
    }
    __syncthreads();
    const float4 me = tile[i + (i >> 7)];

    KDECL(0)  KDECL(1)  KDECL(2)  KDECL(3)  KDECL(4)
    KDECL(5)  KDECL(6)  KDECL(7)  KDECL(8)  KDECL(9)
    KDECL(10) KDECL(11) KDECL(12) KDECL(13) KDECL(14)
    KDECL(15) KDECL(16) KDECL(17) KDECL(18) KDECL(19)

    const int jbase = seg * 128;
    const float4* tseg = &tile[seg * 129];
    for (int t = 0; t < 128; ++t) {
        float4 p = tseg[t];
        float d = me.x * p.x + me.y * p.y + me.z * p.z;
        float v = 2.0f * d - me.w - p.w;
        int j = jbase + t;
        if (v > v19) {
            KSTEP(19,18) KSTEP(18,17) KSTEP(17,16) KSTEP(16,15) KSTEP(15,14)
            KSTEP(14,13) KSTEP(13,12) KSTEP(12,11) KSTEP(11,10) KSTEP(10,9)
            KSTEP(9,8)   KSTEP(8,7)   KSTEP(7,6)   KSTEP(6,5)   KSTEP(5,4)
            KSTEP(4,3)   KSTEP(3,2)   KSTEP(2,1)   KSTEP(1,0)
            if (v > v0) { v0 = v; j0 = j; }
        }
    }
    int* o = idx + ((size_t)b * NP + i) * KNB;
    float hv = v0; int hj = j0;
    for (int r = 0; r < KNB; ++r) {
        float mv = hv; int mj = hj;
#pragma unroll
        for (int s = 1; s <= 8; s <<= 1) {
            float ov = __shfl_xor(mv, s, 64);
            int   oj = __shfl_xor(mj, s, 64);
            if (ov > mv || (ov == mv && oj < mj)) { mv = ov; mj = oj; }
        }
        if (seg == 0) o[r] = mj;
        if (hv == mv && hj == mj) {
            KSHIFT(0,1)   KSHIFT(1,2)   KSHIFT(2,3)   KSHIFT(3,4)   KSHIFT(4,5)
            KSHIFT(5,6)   KSHIFT(6,7)   KSHIFT(7,8)   KSHIFT(8,9)   KSHIFT(9,10)
            KSHIFT(10,11) KSHIFT(11,12) KSHIFT(12,13) KSHIFT(13,14) KSHIFT(14,15)
            KSHIFT(15,16) KSHIFT(16,17) KSHIFT(17,18) KSHIFT(18,19)
            v19 = -3.4e38f; j19 = 0;
        }
        hv = v0; hj = j0;
    }
}

// ==== graph feature, channel-contiguous f[b][s][32]; ch 0-5 real, 6-31 ZERO ====
__global__ void gather_kernel(const float* __restrict__ x, const int* __restrict__ idx,
                              bf16_t* __restrict__ f) {
    int s = blockIdx.x * 256 + threadIdx.x;   // grid.x = 160 -> 40960
    int b = blockIdx.y;
    int n = s / KNB;
    int j = idx[(size_t)b * SS + s];
    const float* xb = x + (size_t)b * 3 * NP;
    ushort4 u0, u1;
    u0.x = f2bf(xb[j]);          u0.y = f2bf(xb[NP + j]);
    u0.z = f2bf(xb[2 * NP + j]); u0.w = f2bf(xb[n]);
    u1.x = f2bf(xb[NP + n]);     u1.y = f2bf(xb[2 * NP + n]);
    u1.z = 0; u1.w = 0;
    ushort4 z4; z4.x = 0; z4.y = 0; z4.z = 0; z4.w = 0;
    bf16_t* fb = f + ((size_t)b * SS + s) * 32;
    *(ushort4*)(fb)      = u0;
    *(ushort4*)(fb + 4)  = u1;
    *(ushort4*)(fb + 8)  = z4;
    *(ushort4*)(fb + 12) = z4;
    *(ushort4*)(fb + 16) = z4;
    *(ushort4*)(fb + 20) = z4;
    *(ushort4*)(fb + 24) = z4;
    *(ushort4*)(fb + 28) = z4;
}

// ==== weights fp32 -> bf16, zero-padded rows ====
__global__ void wconv_kernel(const float* __restrict__ src, bf16_t* __restrict__ dst,
                             int O, int CI, int CIP) {
    int t = blockIdx.x * 256 + threadIdx.x;
    if (t >= O * CIP) return;
    int o = t / CIP, cp = t - o * CIP;
    dst[t] = (cp < CI) ? f2bf(src[o * CI + cp]) : (bf16_t)0;
}

// ==== MFMA conv with LDS-tile epilogue.
// Wave: 64 cout x 32 s (4x2 16x16 tiles). Block: NW waves on s (NW*32 rows),
// 64 couts. Epilogue: dump f32 accumulators into ytile[s_local][cout_local],
// then cooperative store / serial k-group max pool (block = whole groups,
// plain stores, NO atomics) / serial per-channel stats -> per-block partials.
static __device__ __forceinline__ short8_t bnfix(short8_t v, float4 a0, float4 a1,
                                                 float4 d0, float4 d1) {
    short8_t o;
    o[0] = (short)f2bf(fmaxf(fmaf(a0.x, bf2f((unsigned short)v[0]), d0.x), 0.f));
    o[1] = (short)f2bf(fmaxf(fmaf(a0.y, bf2f((unsigned short)v[1]), d0.y), 0.f));
    o[2] = (short)f2bf(fmaxf(fmaf(a0.z, bf2f((unsigned short)v[2]), d0.z), 0.f));
    o[3] = (short)f2bf(fmaxf(fmaf(a0.w, bf2f((unsigned short)v[3]), d0.w), 0.f));
    o[4] = (short)f2bf(fmaxf(fmaf(a1.x, bf2f((unsigned short)v[4]), d1.x), 0.f));
    o[5] = (short)f2bf(fmaxf(fmaf(a1.y, bf2f((unsigned short)v[5]), d1.y), 0.f));
    o[6] = (short)f2bf(fmaxf(fmaf(a1.z, bf2f((unsigned short)v[6]), d1.z), 0.f));
    o[7] = (short)f2bf(fmaxf(fmaf(a1.w, bf2f((unsigned short)v[7]), d1.w), 0.f));
    return o;
}

#define MFMA_BF16 __builtin_amdgcn_mfma_f32_16x16x32_bf16

// C/D layout (m89-verified): value reg r of lane(col,quad) = D[m=quad*4+r][n=col]
#define TILE1(CC, CT, STt) { \
    float* tp = &ytile[w * 32 + (STt) * 16 + col][(CT) * 16 + quad * 4]; \
    tp[0] = CC[0]; tp[1] = CC[1]; tp[2] = CC[2]; tp[3] = CC[3]; }

template<int CIN, int COUT_T, int SROWS, int NW, bool INBN, bool POOL, int ST>
__global__ void mconv(const bf16_t* __restrict__ H, const bf16_t* __restrict__ Wb,
                      const float* __restrict__ abin, void* __restrict__ Yout,
                      bf16_t* __restrict__ poolOut, int chofs,
                      float* __restrict__ part) {
    constexpr int SR = NW * 32;           // local s rows per block
    __shared__ float ytile[SR][65];
    const int tid  = threadIdx.x;
    const int lane = tid & 63, col = lane & 15, quad = lane >> 4, q8 = quad * 8;
    const int w    = tid >> 6;
    const int sb0  = blockIdx.x * SR;
    const int sb   = sb0 + w * 32;
    const int cob  = blockIdx.y * 64;
    const int b    = blockIdx.z;

    const bf16_t* hp0 = H + ((size_t)b * SROWS + sb + col) * CIN + q8;
    const bf16_t* hp1 = hp0 + 16 * CIN;
    const bf16_t* wp  = Wb + (size_t)(cob + col) * CIN + q8;

    f32x4 c00 = {0.f,0.f,0.f,0.f}, c10 = c00, c20 = c00, c30 = c00;
    f32x4 c01 = c00, c11 = c00, c21 = c00, c31 = c00;

#pragma unroll 2
    for (int k0 = 0; k0 < CIN; k0 += 32) {
        short8_t a0 = *(const short8_t*)(wp + k0);
        short8_t a1 = *(const short8_t*)(wp + 16 * CIN + k0);
        short8_t a2 = *(const short8_t*)(wp + 32 * CIN + k0);
        short8_t a3 = *(const short8_t*)(wp + 48 * CIN + k0);
        short8_t b0 = *(const short8_t*)(hp0 + k0);
        short8_t b1 = *(const short8_t*)(hp1 + k0);
        if constexpr (INBN) {
            float4 ca0 = *(const float4*)(abin + k0 + q8);
            float4 ca1 = *(const float4*)(abin + k0 + q8 + 4);
            float4 cd0 = *(const float4*)(abin + CIN + k0 + q8);
            float4 cd1 = *(const float4*)(abin + CIN + k0 + q8 + 4);
            b0 = bnfix(b0, ca0, ca1, cd0, cd1);
            b1 = bnfix(b1, ca0, ca1, cd0, cd1);
        }
        c00 = MFMA_BF16(a0, b0, c00, 0, 0, 0);
        c10 = MFMA_BF16(a1, b0, c10, 0, 0, 0);
        c20 = MFMA_BF16(a2, b0, c20, 0, 0, 0);
        c30 = MFMA_BF16(a3, b0, c30, 0, 0, 0);
        c01 = MFMA_BF16(a0, b1, c01, 0, 0, 0);
        c11 = MFMA_BF16(a1, b1, c11, 0, 0, 0);
        c21 = MFMA_BF16(a2, b1, c21, 0, 0, 0);
        c31 = MFMA_BF16(a3, b1, c31, 0, 0, 0);
    }

    TILE1(c00,0,0) TILE1(c10,1,0) TILE1(c20,2,0) TILE1(c30,3,0)
    TILE1(c01,0,1) TILE1(c11,1,1) TILE1(c21,2,1) TILE1(c31,3,1)
    __syncthreads();

    if constexpr (ST == 1) {   // bf16 store, coalesced from tile
        for (int i = tid; i < SR * 16; i += NW * 64) {
            int row = i >> 4, c4 = (i & 15) * 4;
            ushort4 o_;
            o_.x = f2bf(ytile[row][c4]);     o_.y = f2bf(ytile[row][c4 + 1]);
            o_.z = f2bf(ytile[row][c4 + 2]); o_.w = f2bf(ytile[row][c4 + 3]);
            *(ushort4*)((bf16_t*)Yout +
                ((size_t)b * SROWS + sb0 + row) * COUT_T + cob + c4) = o_;
        }
    }
    if constexpr (ST == 2) {   // f32 store
        for (int i = tid; i < SR * 16; i += NW * 64) {
            int row = i >> 4, c4 = (i & 15) * 4;
            float4 o_ = make_float4(ytile[row][c4], ytile[row][c4 + 1],
                                    ytile[row][c4 + 2], ytile[row][c4 + 3]);
            *(float4*)((float*)Yout +
                ((size_t)b * SROWS + sb0 + row) * COUT_T + cob + c4) = o_;
        }
    }

    if constexpr (POOL) {      // SR=160 = exactly 8 whole k-groups: plain stores
        const int nbase = blockIdx.x * 8;
        for (int i = tid; i < 8 * 64; i += NW * 64) {
            int nl = i >> 6, c = i & 63;
            float m = ytile[nl * 20][c];
#pragma unroll
            for (int k = 1; k < KNB; ++k) m = fmaxf(m, ytile[nl * 20 + k][c]);
            poolOut[((size_t)b * NP + nbase + nl) * 512 + chofs + cob + c] = f2bf(m);
        }
    }

    // BN stats: one thread per channel, serial over SR rows -> block partials
    if (tid < 64) {
        float sv = 0.f, qv = 0.f;
        for (int s = 0; s < SR; ++s) {
            float v = ytile[s][tid];
            sv += v; qv += v * v;
        }
        int blkLin = ((int)blockIdx.z * gridDim.y + blockIdx.y) * gridDim.x
                     + blockIdx.x;
        part[(size_t)blkLin * 128 + tid] = sv;
        part[(size_t)blkLin * 128 + 64 + tid] = qv;
    }
}

// ==== per-block stats partials -> BN affine coefs ====
__global__ void bn_finalize(const float* __restrict__ part, int GX, int GY,
                            const float* __restrict__ g, const float* __restrict__ bt,
                            float* __restrict__ ab, int C, float invM) {
    __shared__ float red[256][2];
    int tid = threadIdx.x;
    int c = blockIdx.x * 64 + (tid & 63);
    int chunk = tid >> 6;
    int gcg = c >> 6, lc = c & 63;
    float sv = 0.f, qv = 0.f;
    int total = GX * BB;
    for (int i = chunk; i < total; i += 4) {
        int z = i / GX, xx = i - z * GX;
        size_t base = ((size_t)((z * GY + gcg) * GX + xx)) * 128;
        sv += part[base + lc];
        qv += part[base + 64 + lc];
    }
    red[tid][0] = sv; red[tid][1] = qv;
    __syncthreads();
    if (tid < 64) {
        sv = red[tid][0] + red[tid+64][0] + red[tid+128][0] + red[tid+192][0];
        qv = red[tid][1] + red[tid+64][1] + red[tid+128][1] + red[tid+192][1];
        float mean = sv * invM;
        float var  = fmaxf(qv * invM - mean * mean, 0.f);
        float a = g[c] * rsqrtf(var + 1e-5f);
        ab[c] = a;
        ab[C + c] = fmaf(-mean, a, bt[c]);
    }
}

// ==== pooled raw bf16 -> BN+ReLU -> xcat bf16 [b][n][512] ====
__global__ void pool_convert(const bf16_t* __restrict__ pr, const float* __restrict__ ab,
                             bf16_t* __restrict__ xc, int C, int chofs, int logC) {
    int t = blockIdx.x * 256 + threadIdx.x;
    int c = t & (C - 1);
    int rest = t >> logC;
    int n = rest & (NP - 1);
    int b = rest >> 11;
    size_t p = ((size_t)b * NP + n) * 512 + chofs + c;
    float v = bf2f(pr[p]);
    xc[p] = f2bf(fmaxf(fmaf(ab[c], v, ab[C + c]), 0.f));
}

// ==== y5 [b][n][512] f32 -> BN+ReLU -> out [b][1024][n] (pad 512-1023 zero) ====
__global__ void out_kernel(const float* __restrict__ y5, const float* __restrict__ ab,
                           float* __restrict__ out) {
    int t = blockIdx.x * 256 + threadIdx.x;   // 4.19M threads exact
    int n = t & (NP - 1);
    int c4 = (t >> 11) & 255;
    int b = t >> 19;
    int c0 = c4 * 4;
    float4 v = make_float4(0.f, 0.f, 0.f, 0.f);
    if (c0 < 512) {
        float4 yv = *(const float4*)(y5 + ((size_t)b * NP + n) * 512 + c0);
        float4 av = *(const float4*)(ab + c0);
        float4 dv = *(const float4*)(ab + 512 + c0);
        v.x = fmaxf(fmaf(av.x, yv.x, dv.x), 0.f);
        v.y = fmaxf(fmaf(av.y, yv.y, dv.y), 0.f);
        v.z = fmaxf(fmaf(av.z, yv.z, dv.z), 0.f);
        v.w = fmaxf(fmaf(av.w, yv.w, dv.w), 0.f);
    }
    float* ob = out + ((size_t)b * 1024 + c0) * NP + n;
    ob[0] = v.x; ob[NP] = v.y; ob[2 * NP] = v.z; ob[3 * NP] = v.w;
}

extern "C" void kernel_launch(void* const* d_in, const int* in_sizes, int n_in,
                              void* d_out, int out_size, void* d_ws, size_t ws_size,
                              hipStream_t stream) {
    (void)in_sizes; (void)n_in; (void)out_size; (void)ws_size;
    const float* x  = (const float*)d_in[0];
    const float* W1 = (const float*)d_in[1];
    const float* W2 = (const float*)d_in[2];
    const float* W3 = (const float*)d_in[3];
    const float* W4 = (const float*)d_in[4];
    const float* W5 = (const float*)d_in[5];
    const float* g1 = (const float*)d_in[6];  const float* b1 = (const float*)d_in[7];
    const float* g2 = (const float*)d_in[8];  const float* b2 = (const float*)d_in[9];
    const float* g3 = (const float*)d_in[10]; const float* b3 = (const float*)d_in[11];
    const float* g4 = (const float*)d_in[12]; const float* b4 = (const float*)d_in[13];
    const float* g5 = (const float*)d_in[14]; const float* b5 = (const float*)d_in[15];

    // workspace (~170 MB), lifetime-aliased (same offsets as R7):
    // A @0 (41.94M): f | y2 | y5      B @41943040 (83.89M): y1 | y3
    char* ws = (char*)d_ws;
    bf16_t* f    = (bf16_t*)(ws + 0);
    bf16_t* y2   = (bf16_t*)(ws + 0);
    float*  y5   = (float*) (ws + 0);
    bf16_t* y1   = (bf16_t*)(ws + 41943040);
    bf16_t* y3   = (bf16_t*)(ws + 41943040);
    bf16_t* poolraw = (bf16_t*)(ws + 125829120);   // [8][2048][512] raw pooled
    bf16_t* xcat    = (bf16_t*)(ws + 142606336);   // [8][2048][512] post-BN
    bf16_t* Wball   = (bf16_t*)(ws + 159383552);
    bf16_t* W1b = Wball;            // 64x32
    bf16_t* W2b = Wball + 2048;     // 64x64
    bf16_t* W3b = Wball + 6144;     // 128x64
    bf16_t* W4b = Wball + 14336;    // 256x128
    bf16_t* W5b = Wball + 47104;    // 512x512
    float* p1 = (float*)(ws + 160002048);
    float* p2 = (float*)(ws + 161050624);
    float* p3 = (float*)(ws + 162099200);
    float* p4 = (float*)(ws + 164196352);
    float* p5 = (float*)(ws + 168390656);
    float* ab = (float*)(ws + 168914944);
    int*  idx = (int*)  (ws + 168923136);

    float* ab1 = ab;       float* ab2 = ab + 128;  float* ab3 = ab + 256;
    float* ab4 = ab + 512; float* ab5 = ab + 1024;
    const float invM14 = 1.f / (float)(BB * SS);
    const float invM5  = 1.f / (float)(BB * NP);

    wconv_kernel<<<8,    256, 0, stream>>>(W1, W1b, 64, 6, 32);
    wconv_kernel<<<16,   256, 0, stream>>>(W2, W2b, 64, 64, 64);
    wconv_kernel<<<32,   256, 0, stream>>>(W3, W3b, 128, 64, 64);
    wconv_kernel<<<128,  256, 0, stream>>>(W4, W4b, 256, 128, 128);
    wconv_kernel<<<1024, 256, 0, stream>>>(W5, W5b, 512, 512, 512);

    knn_kernel<<<1024, 256, 0, stream>>>(x, idx);
    gather_kernel<<<dim3(160, BB), 256, 0, stream>>>(x, idx, f);

    // L1: 6(pad32) -> 64
    mconv<32, 64, SS, 5, false, true, 1><<<dim3(256, 1, BB), 320, 0, stream>>>(
        f, W1b, nullptr, y1, poolraw, 0, p1);
    bn_finalize<<<1, 256, 0, stream>>>(p1, 256, 1, g1, b1, ab1, 64, invM14);
    pool_convert<<<4096, 256, 0, stream>>>(poolraw, ab1, xcat, 64, 0, 6);

    // L2: 64 -> 64 (BN1 on load)
    mconv<64, 64, SS, 5, true, true, 1><<<dim3(256, 1, BB), 320, 0, stream>>>(
        y1, W2b, ab1, y2, poolraw, 64, p2);
    bn_finalize<<<1, 256, 0, stream>>>(p2, 256, 1, g2, b2, ab2, 64, invM14);
    pool_convert<<<4096, 256, 0, stream>>>(poolraw, ab2, xcat, 64, 64, 6);

    // L3: 64 -> 128
    mconv<64, 128, SS, 5, true, true, 1><<<dim3(256, 2, BB), 320, 0, stream>>>(
        y2, W3b, ab2, y3, poolraw, 128, p3);
    bn_finalize<<<2, 256, 0, stream>>>(p3, 256, 2, g3, b3, ab3, 128, invM14);
    pool_convert<<<8192, 256, 0, stream>>>(poolraw, ab3, xcat, 128, 128, 7);

    // L4: 128 -> 256, pool-only (y4 never materialized)
    mconv<128, 256, SS, 5, true, true, 0><<<dim3(256, 4, BB), 320, 0, stream>>>(
        y3, W4b, ab3, nullptr, poolraw, 256, p4);
    bn_finalize<<<4, 256, 0, stream>>>(p4, 256, 4, g4, b4, ab4, 256, invM14);
    pool_convert<<<16384, 256, 0, stream>>>(poolraw, ab4, xcat, 256, 256, 8);

    // L5: 512 -> 512 over [b][2048][512]
    mconv<512, 512, NP, 4, false, false, 2><<<dim3(16, 8, BB), 256, 0, stream>>>(
        xcat, W5b, nullptr, y5, nullptr, 0, p5);
    bn_finalize<<<8, 256, 0, stream>>>(p5, 16, 8, g5, b5, ab5, 512, invM5);

    out_kernel<<<16384, 256, 0, stream>>>(y5, ab5, (float*)d_out);
}

// Round 9
// 657.546 us; speedup vs baseline: 4.2426x; 1.7303x over previous
//
#include <hip/hip_runtime.h>

#define BB  8
#define NP  2048
#define KNB 20
#define SS  40960   // spatial per batch, layers 1-4

typedef unsigned short bf16_t;
typedef __attribute__((ext_vector_type(8))) short short8_t;   // MFMA A/B frag (8 bf16)
typedef __attribute__((ext_vector_type(4))) float f32x4;      // MFMA C/D frag

static __device__ __forceinline__ float bf2f(unsigned short u) {
    return __uint_as_float(((unsigned)u) << 16);
}
static __device__ __forceinline__ bf16_t f2bf(float f) {
    unsigned u = __float_as_uint(f);
    return (bf16_t)((u + 0x7fffu + ((u >> 16) & 1u)) >> 16);   // RNE
}

// ==== kNN (unchanged: register top-20, 16x16 shfl merge; verified R3-R8) ====
#define KDECL(t) float v##t = -3.4e38f; int j##t = 0;
#define KSTEP(t, p) \
    { if (v > v##p) { v##t = v##p; j##t = j##p; } \
      else if (v > v##t) { v##t = v; j##t = j; } }
#define KSHIFT(t, n) v##t = v##n; j##t = j##n;

__global__ __launch_bounds__(256) void knn_kernel(const float* __restrict__ x,
                                                  int* __restrict__ idx) {
    __shared__ float4 tile[2064];
    const int tid  = threadIdx.x;
    const int b    = blockIdx.x >> 7;
    const int pblk = blockIdx.x & 127;
    const int pl   = tid >> 4;
    const int seg  = tid & 15;
    const int i    = pblk * 16 + pl;
    const float* xb = x + (size_t)b * 3 * NP;

    for (int j = tid; j < NP; j += 256) {
        float a0 = xb[j], a1 = xb[NP + j], a2 = xb[2 * NP + j];
        tile[j + (j >> 7)] = make_float4(a0, a1, a2, a0 * a0 + a1 * a1 + a2 * a2);
    }
    __syncthreads();
    const float4 me = tile[i + (i >> 7)];

    KDECL(0)  KDECL(1)  KDECL(2)  KDECL(3)  KDECL(4)
    KDECL(5)  KDECL(6)  KDECL(7)  KDECL(8)  KDECL(9)
    KDECL(10) KDECL(11) KDECL(12) KDECL(13) KDECL(14)
    KDECL(15) KDECL(16) KDECL(17) KDECL(18) KDECL(19)

    const int jbase = seg * 128;
    const float4* tseg = &tile[seg * 129];
    for (int t = 0; t < 128; ++t) {
        float4 p = tseg[t];
        float d = me.x * p.x + me.y * p.y + me.z * p.z;
        float v = 2.0f * d - me.w - p.w;
        int j = jbase + t;
        if (v > v19) {
            KSTEP(19,18) KSTEP(18,17) KSTEP(17,16) KSTEP(16,15) KSTEP(15,14)
            KSTEP(14,13) KSTEP(13,12) KSTEP(12,11) KSTEP(11,10) KSTEP(10,9)
            KSTEP(9,8)   KSTEP(8,7)   KSTEP(7,6)   KSTEP(6,5)   KSTEP(5,4)
            KSTEP(4,3)   KSTEP(3,2)   KSTEP(2,1)   KSTEP(1,0)
            if (v > v0) { v0 = v; j0 = j; }
        }
    }
    int* o = idx + ((size_t)b * NP + i) * KNB;
    float hv = v0; int hj = j0;
    for (int r = 0; r < KNB; ++r) {
        float mv = hv; int mj = hj;
#pragma unroll
        for (int s = 1; s <= 8; s <<= 1) {
            float ov = __shfl_xor(mv, s, 64);
            int   oj = __shfl_xor(mj, s, 64);
            if (ov > mv || (ov == mv && oj < mj)) { mv = ov; mj = oj; }
        }
        if (seg == 0) o[r] = mj;
        if (hv == mv && hj == mj) {
            KSHIFT(0,1)   KSHIFT(1,2)   KSHIFT(2,3)   KSHIFT(3,4)   KSHIFT(4,5)
            KSHIFT(5,6)   KSHIFT(6,7)   KSHIFT(7,8)   KSHIFT(8,9)   KSHIFT(9,10)
            KSHIFT(10,11) KSHIFT(11,12) KSHIFT(12,13) KSHIFT(13,14) KSHIFT(14,15)
            KSHIFT(15,16) KSHIFT(16,17) KSHIFT(17,18) KSHIFT(18,19)
            v19 = -3.4e38f; j19 = 0;
        }
        hv = v0; hj = j0;
    }
}

// ==== graph feature, channel-contiguous f[b][s][32]; ch 0-5 real, 6-31 ZERO ====
__global__ void gather_kernel(const float* __restrict__ x, const int* __restrict__ idx,
                              bf16_t* __restrict__ f) {
    int s = blockIdx.x * 256 + threadIdx.x;
    int b = blockIdx.y;
    int n = s / KNB;
    int j = idx[(size_t)b * SS + s];
    const float* xb = x + (size_t)b * 3 * NP;
    ushort4 u0, u1;
    u0.x = f2bf(xb[j]);          u0.y = f2bf(xb[NP + j]);
    u0.z = f2bf(xb[2 * NP + j]); u0.w = f2bf(xb[n]);
    u1.x = f2bf(xb[NP + n]);     u1.y = f2bf(xb[2 * NP + n]);
    u1.z = 0; u1.w = 0;
    ushort4 z4; z4.x = 0; z4.y = 0; z4.z = 0; z4.w = 0;
    bf16_t* fb = f + ((size_t)b * SS + s) * 32;
    *(ushort4*)(fb)      = u0;
    *(ushort4*)(fb + 4)  = u1;
    *(ushort4*)(fb + 8)  = z4;
    *(ushort4*)(fb + 12) = z4;
    *(ushort4*)(fb + 16) = z4;
    *(ushort4*)(fb + 20) = z4;
    *(ushort4*)(fb + 24) = z4;
    *(ushort4*)(fb + 28) = z4;
}

// ==== weights fp32 -> bf16, zero-padded rows ====
__global__ void wconv_kernel(const float* __restrict__ src, bf16_t* __restrict__ dst,
                             int O, int CI, int CIP) {
    int t = blockIdx.x * 256 + threadIdx.x;
    if (t >= O * CIP) return;
    int o = t / CIP, cp = t - o * CIP;
    dst[t] = (cp < CI) ? f2bf(src[o * CI + cp]) : (bf16_t)0;
}

// ==== zero the layer-stats accumulators (2048 floats) ====
__global__ void zstats_kernel(float* __restrict__ p) {
    p[blockIdx.x * 256 + threadIdx.x] = 0.f;
}

// ==== MFMA conv, bf16 LDS-tile epilogue + parallel chunked stats.
// Wave: 64 cout x 32 s. Block: NW waves on s (SR=NW*32 rows), 64 couts.
// Epilogue: accs -> bf16 ytile[s][cout] (verified C/D mapping: m=cout=quad*4+r,
// n=s=col), then coalesced store / whole-k-group max pool (plain stores) /
// chunked per-channel stats -> 128 global atomicAdds per block.
static __device__ __forceinline__ short8_t bnfix(short8_t v, float4 a0, float4 a1,
                                                 float4 d0, float4 d1) {
    short8_t o;
    o[0] = (short)f2bf(fmaxf(fmaf(a0.x, bf2f((unsigned short)v[0]), d0.x), 0.f));
    o[1] = (short)f2bf(fmaxf(fmaf(a0.y, bf2f((unsigned short)v[1]), d0.y), 0.f));
    o[2] = (short)f2bf(fmaxf(fmaf(a0.z, bf2f((unsigned short)v[2]), d0.z), 0.f));
    o[3] = (short)f2bf(fmaxf(fmaf(a0.w, bf2f((unsigned short)v[3]), d0.w), 0.f));
    o[4] = (short)f2bf(fmaxf(fmaf(a1.x, bf2f((unsigned short)v[4]), d1.x), 0.f));
    o[5] = (short)f2bf(fmaxf(fmaf(a1.y, bf2f((unsigned short)v[5]), d1.y), 0.f));
    o[6] = (short)f2bf(fmaxf(fmaf(a1.z, bf2f((unsigned short)v[6]), d1.z), 0.f));
    o[7] = (short)f2bf(fmaxf(fmaf(a1.w, bf2f((unsigned short)v[7]), d1.w), 0.f));
    return o;
}

#define MFMA_BF16 __builtin_amdgcn_mfma_f32_16x16x32_bf16

#define TILE1(CC, CT, STt) { \
    bf16_t* tp = &ytile[w * 32 + (STt) * 16 + col][(CT) * 16 + quad * 4]; \
    tp[0] = f2bf(CC[0]); tp[1] = f2bf(CC[1]); \
    tp[2] = f2bf(CC[2]); tp[3] = f2bf(CC[3]); }

template<int CIN, int COUT_T, int SROWS, int NW, bool INBN, bool POOL, bool ST>
__global__ void mconv(const bf16_t* __restrict__ H, const bf16_t* __restrict__ Wb,
                      const float* __restrict__ abin, bf16_t* __restrict__ Yout,
                      bf16_t* __restrict__ poolOut, int chofs,
                      float* __restrict__ stats) {
    constexpr int SR = NW * 32;
    __shared__ bf16_t ytile[SR][68];      // pad 68: 8B-aligned rows, low conflicts
    __shared__ float redS[NW][64];
    __shared__ float redQ[NW][64];
    const int tid  = threadIdx.x;
    const int lane = tid & 63, col = lane & 15, quad = lane >> 4, q8 = quad * 8;
    const int w    = tid >> 6;
    const int sb0  = blockIdx.x * SR;
    const int sb   = sb0 + w * 32;
    const int cob  = blockIdx.y * 64;
    const int b    = blockIdx.z;

    const bf16_t* hp0 = H + ((size_t)b * SROWS + sb + col) * CIN + q8;
    const bf16_t* hp1 = hp0 + 16 * CIN;
    const bf16_t* wp  = Wb + (size_t)(cob + col) * CIN + q8;

    f32x4 c00 = {0.f,0.f,0.f,0.f}, c10 = c00, c20 = c00, c30 = c00;
    f32x4 c01 = c00, c11 = c00, c21 = c00, c31 = c00;

#pragma unroll 2
    for (int k0 = 0; k0 < CIN; k0 += 32) {
        short8_t a0 = *(const short8_t*)(wp + k0);
        short8_t a1 = *(const short8_t*)(wp + 16 * CIN + k0);
        short8_t a2 = *(const short8_t*)(wp + 32 * CIN + k0);
        short8_t a3 = *(const short8_t*)(wp + 48 * CIN + k0);
        short8_t b0 = *(const short8_t*)(hp0 + k0);
        short8_t b1 = *(const short8_t*)(hp1 + k0);
        if constexpr (INBN) {
            float4 ca0 = *(const float4*)(abin + k0 + q8);
            float4 ca1 = *(const float4*)(abin + k0 + q8 + 4);
            float4 cd0 = *(const float4*)(abin + CIN + k0 + q8);
            float4 cd1 = *(const float4*)(abin + CIN + k0 + q8 + 4);
            b0 = bnfix(b0, ca0, ca1, cd0, cd1);
            b1 = bnfix(b1, ca0, ca1, cd0, cd1);
        }
        c00 = MFMA_BF16(a0, b0, c00, 0, 0, 0);
        c10 = MFMA_BF16(a1, b0, c10, 0, 0, 0);
        c20 = MFMA_BF16(a2, b0, c20, 0, 0, 0);
        c30 = MFMA_BF16(a3, b0, c30, 0, 0, 0);
        c01 = MFMA_BF16(a0, b1, c01, 0, 0, 0);
        c11 = MFMA_BF16(a1, b1, c11, 0, 0, 0);
        c21 = MFMA_BF16(a2, b1, c21, 0, 0, 0);
        c31 = MFMA_BF16(a3, b1, c31, 0, 0, 0);
    }

    TILE1(c00,0,0) TILE1(c10,1,0) TILE1(c20,2,0) TILE1(c30,3,0)
    TILE1(c01,0,1) TILE1(c11,1,1) TILE1(c21,2,1) TILE1(c31,3,1)
    __syncthreads();

    if constexpr (ST) {   // bf16 store, coalesced from tile
        for (int i = tid; i < SR * 16; i += NW * 64) {
            int row = i >> 4, c4 = (i & 15) * 4;
            *(ushort4*)(Yout + ((size_t)b * SROWS + sb0 + row) * COUT_T + cob + c4)
                = *(const ushort4*)&ytile[row][c4];
        }
    }

    if constexpr (POOL) { // SR=160 = exactly 8 whole k-groups: plain stores
        const int nbase = blockIdx.x * 8;
        for (int i = tid; i < 8 * 64; i += NW * 64) {
            int nl = i >> 6, c = i & 63;
            float m = bf2f(ytile[nl * 20][c]);
#pragma unroll
            for (int k = 1; k < KNB; ++k) m = fmaxf(m, bf2f(ytile[nl * 20 + k][c]));
            poolOut[((size_t)b * NP + nbase + nl) * 512 + chofs + cob + c] = f2bf(m);
        }
    }

    // BN stats: NW chunks of 32 rows in parallel -> LDS partials -> global atomics
    {
        int c = tid & 63, ch = tid >> 6;
        float sv = 0.f, qv = 0.f;
        for (int s = ch * 32; s < ch * 32 + 32; ++s) {
            float v = bf2f(ytile[s][c]);
            sv += v; qv += v * v;
        }
        redS[ch][c] = sv; redQ[ch][c] = qv;
    }
    __syncthreads();
    if (tid < 64) {
        float sv = 0.f, qv = 0.f;
#pragma unroll
        for (int ch = 0; ch < NW; ++ch) { sv += redS[ch][tid]; qv += redQ[ch][tid]; }
        atomicAdd(&stats[cob + tid], sv);
        atomicAdd(&stats[COUT_T + cob + tid], qv);
    }
}

// ==== summed stats -> BN affine coefs (trivial) ====
__global__ void bn_finalize(const float* __restrict__ stats,
                            const float* __restrict__ g, const float* __restrict__ bt,
                            float* __restrict__ ab, int C, float invM) {
    int c = blockIdx.x * 64 + threadIdx.x;
    if (c >= C) return;
    float mean = stats[c] * invM;
    float var  = fmaxf(stats[C + c] * invM - mean * mean, 0.f);
    float a = g[c] * rsqrtf(var + 1e-5f);
    ab[c] = a;
    ab[C + c] = fmaf(-mean, a, bt[c]);
}

// ==== pooled raw bf16 -> BN+ReLU -> xcat bf16 [b][n][512] ====
__global__ void pool_convert(const bf16_t* __restrict__ pr, const float* __restrict__ ab,
                             bf16_t* __restrict__ xc, int C, int chofs, int logC) {
    int t = blockIdx.x * 256 + threadIdx.x;
    int c = t & (C - 1);
    int rest = t >> logC;
    int n = rest & (NP - 1);
    int b = rest >> 11;
    size_t p = ((size_t)b * NP + n) * 512 + chofs + c;
    float v = bf2f(pr[p]);
    xc[p] = f2bf(fmaxf(fmaf(ab[c], v, ab[C + c]), 0.f));
}

// ==== y5 bf16 [b][n][512] -> BN+ReLU -> out f32 [b][1024][n] (pad zero) ====
__global__ void out_kernel(const bf16_t* __restrict__ y5, const float* __restrict__ ab,
                           float* __restrict__ out) {
    int t = blockIdx.x * 256 + threadIdx.x;
    int n = t & (NP - 1);
    int c4 = (t >> 11) & 255;
    int b = t >> 19;
    int c0 = c4 * 4;
    float4 v = make_float4(0.f, 0.f, 0.f, 0.f);
    if (c0 < 512) {
        ushort4 yv = *(const ushort4*)(y5 + ((size_t)b * NP + n) * 512 + c0);
        float4 av = *(const float4*)(ab + c0);
        float4 dv = *(const float4*)(ab + 512 + c0);
        v.x = fmaxf(fmaf(av.x, bf2f(yv.x), dv.x), 0.f);
        v.y = fmaxf(fmaf(av.y, bf2f(yv.y), dv.y), 0.f);
        v.z = fmaxf(fmaf(av.z, bf2f(yv.z), dv.z), 0.f);
        v.w = fmaxf(fmaf(av.w, bf2f(yv.w), dv.w), 0.f);
    }
    float* ob = out + ((size_t)b * 1024 + c0) * NP + n;
    ob[0] = v.x; ob[NP] = v.y; ob[2 * NP] = v.z; ob[3 * NP] = v.w;
}

extern "C" void kernel_launch(void* const* d_in, const int* in_sizes, int n_in,
                              void* d_out, int out_size, void* d_ws, size_t ws_size,
                              hipStream_t stream) {
    (void)in_sizes; (void)n_in; (void)out_size; (void)ws_size;
    const float* x  = (const float*)d_in[0];
    const float* W1 = (const float*)d_in[1];
    const float* W2 = (const float*)d_in[2];
    const float* W3 = (const float*)d_in[3];
    const float* W4 = (const float*)d_in[4];
    const float* W5 = (const float*)d_in[5];
    const float* g1 = (const float*)d_in[6];  const float* b1 = (const float*)d_in[7];
    const float* g2 = (const float*)d_in[8];  const float* b2 = (const float*)d_in[9];
    const float* g3 = (const float*)d_in[10]; const float* b3 = (const float*)d_in[11];
    const float* g4 = (const float*)d_in[12]; const float* b4 = (const float*)d_in[13];
    const float* g5 = (const float*)d_in[14]; const float* b5 = (const float*)d_in[15];

    // workspace, lifetime-aliased (same arena scheme as R8):
    // A @0 (41.94M): f | y2 | y5(bf16)   B @41943040 (83.89M): y1 | y3
    char* ws = (char*)d_ws;
    bf16_t* f    = (bf16_t*)(ws + 0);
    bf16_t* y2   = (bf16_t*)(ws + 0);
    bf16_t* y5   = (bf16_t*)(ws + 0);
    bf16_t* y1   = (bf16_t*)(ws + 41943040);
    bf16_t* y3   = (bf16_t*)(ws + 41943040);
    bf16_t* poolraw = (bf16_t*)(ws + 125829120);   // [8][2048][512] raw pooled
    bf16_t* xcat    = (bf16_t*)(ws + 142606336);   // [8][2048][512] post-BN
    bf16_t* Wball   = (bf16_t*)(ws + 159383552);
    bf16_t* W1b = Wball;            // 64x32
    bf16_t* W2b = Wball + 2048;     // 64x64
    bf16_t* W3b = Wball + 6144;     // 128x64
    bf16_t* W4b = Wball + 14336;    // 256x128
    bf16_t* W5b = Wball + 47104;    // 512x512
    float* stats = (float*)(ws + 160002048);   // 2048 floats, zeroed per launch
    float* ab    = (float*)(ws + 160010240);   // 2048 floats
    int*  idx    = (int*)  (ws + 160018432);   // 1.31MB

    float* st1 = stats;        float* st2 = stats + 128;  float* st3 = stats + 256;
    float* st4 = stats + 512;  float* st5 = stats + 1024;
    float* ab1 = ab;       float* ab2 = ab + 128;  float* ab3 = ab + 256;
    float* ab4 = ab + 512; float* ab5 = ab + 1024;
    const float invM14 = 1.f / (float)(BB * SS);
    const float invM5  = 1.f / (float)(BB * NP);

    zstats_kernel<<<8, 256, 0, stream>>>(stats);
    wconv_kernel<<<8,    256, 0, stream>>>(W1, W1b, 64, 6, 32);
    wconv_kernel<<<16,   256, 0, stream>>>(W2, W2b, 64, 64, 64);
    wconv_kernel<<<32,   256, 0, stream>>>(W3, W3b, 128, 64, 64);
    wconv_kernel<<<128,  256, 0, stream>>>(W4, W4b, 256, 128, 128);
    wconv_kernel<<<1024, 256, 0, stream>>>(W5, W5b, 512, 512, 512);

    knn_kernel<<<1024, 256, 0, stream>>>(x, idx);
    gather_kernel<<<dim3(160, BB), 256, 0, stream>>>(x, idx, f);

    // L1: 6(pad32) -> 64
    mconv<32, 64, SS, 5, false, true, true><<<dim3(256, 1, BB), 320, 0, stream>>>(
        f, W1b, nullptr, y1, poolraw, 0, st1);
    bn_finalize<<<1, 64, 0, stream>>>(st1, g1, b1, ab1, 64, invM14);
    pool_convert<<<4096, 256, 0, stream>>>(poolraw, ab1, xcat, 64, 0, 6);

    // L2: 64 -> 64 (BN1 on load)
    mconv<64, 64, SS, 5, true, true, true><<<dim3(256, 1, BB), 320, 0, stream>>>(
        y1, W2b, ab1, y2, poolraw, 64, st2);
    bn_finalize<<<1, 64, 0, stream>>>(st2, g2, b2, ab2, 64, invM14);
    pool_convert<<<4096, 256, 0, stream>>>(poolraw, ab2, xcat, 64, 64, 6);

    // L3: 64 -> 128
    mconv<64, 128, SS, 5, true, true, true><<<dim3(256, 2, BB), 320, 0, stream>>>(
        y2, W3b, ab2, y3, poolraw, 128, st3);
    bn_finalize<<<2, 64, 0, stream>>>(st3, g3, b3, ab3, 128, invM14);
    pool_convert<<<8192, 256, 0, stream>>>(poolraw, ab3, xcat, 128, 128, 7);

    // L4: 128 -> 256, pool-only (y4 never materialized)
    mconv<128, 256, SS, 5, true, true, false><<<dim3(256, 4, BB), 320, 0, stream>>>(
        y3, W4b, ab3, nullptr, poolraw, 256, st4);
    bn_finalize<<<4, 64, 0, stream>>>(st4, g4, b4, ab4, 256, invM14);
    pool_convert<<<16384, 256, 0, stream>>>(poolraw, ab4, xcat, 256, 256, 8);

    // L5: 512 -> 512 over [b][2048][512], bf16 out
    mconv<512, 512, NP, 4, false, false, true><<<dim3(16, 8, BB), 256, 0, stream>>>(
        xcat, W5b, nullptr, y5, nullptr, 0, st5);
    bn_finalize<<<8, 64, 0, stream>>>(st5, g5, b5, ab5, 512, invM5);

    out_kernel<<<16384, 256, 0, stream>>>(y5, ab5, (float*)d_out);
}

// Round 10
// 533.981 us; speedup vs baseline: 5.2243x; 1.2314x over previous
//
#include <hip/hip_runtime.h>

#define BB  8
#define NP  2048
#define KNB 20
#define SS  40960   // spatial per batch, layers 1-4

typedef unsigned short bf16_t;
typedef __attribute__((ext_vector_type(8))) short short8_t;   // MFMA A/B frag (8 bf16)
typedef __attribute__((ext_vector_type(4))) float f32x4;      // MFMA C/D frag

static __device__ __forceinline__ float bf2f(unsigned short u) {
    return __uint_as_float(((unsigned)u) << 16);
}
static __device__ __forceinline__ bf16_t f2bf(float f) {
    unsigned u = __float_as_uint(f);
    return (bf16_t)((u + 0x7fffu + ((u >> 16) & 1u)) >> 16);   // RNE
}

// ==== kNN (unchanged: register top-20, 16x16 shfl merge; verified R3-R9) ====
#define KDECL(t) float v##t = -3.4e38f; int j##t = 0;
#define KSTEP(t, p) \
    { if (v > v##p) { v##t = v##p; j##t = j##p; } \
      else if (v > v##t) { v##t = v; j##t = j; } }
#define KSHIFT(t, n) v##t = v##n; j##t = j##n;

__global__ __launch_bounds__(256) void knn_kernel(const float* __restrict__ x,
                                                  int* __restrict__ idx) {
    __shared__ float4 tile[2064];
    const int tid  = threadIdx.x;
    const int b    = blockIdx.x >> 7;
    const int pblk = blockIdx.x & 127;
    const int pl   = tid >> 4;
    const int seg  = tid & 15;
    const int i    = pblk * 16 + pl;
    const float* xb = x + (size_t)b * 3 * NP;

    for (int j = tid; j < NP; j += 256) {
        float a0 = xb[j], a1 = xb[NP + j], a2 = xb[2 * NP + j];
        tile[j + (j >> 7)] = make_float4(a0, a1, a2, a0 * a0 + a1 * a1 + a2 * a2);
    }
    __syncthreads();
    const float4 me = tile[i + (i >> 7)];

    KDECL(0)  KDECL(1)  KDECL(2)  KDECL(3)  KDECL(4)
    KDECL(5)  KDECL(6)  KDECL(7)  KDECL(8)  KDECL(9)
    KDECL(10) KDECL(11) KDECL(12) KDECL(13) KDECL(14)
    KDECL(15) KDECL(16) KDECL(17) KDECL(18) KDECL(19)

    const int jbase = seg * 128;
    const float4* tseg = &tile[seg * 129];
    for (int t = 0; t < 128; ++t) {
        float4 p = tseg[t];
        float d = me.x * p.x + me.y * p.y + me.z * p.z;
        float v = 2.0f * d - me.w - p.w;
        int j = jbase + t;
        if (v > v19) {
            KSTEP(19,18) KSTEP(18,17) KSTEP(17,16) KSTEP(16,15) KSTEP(15,14)
            KSTEP(14,13) KSTEP(13,12) KSTEP(12,11) KSTEP(11,10) KSTEP(10,9)
            KSTEP(9,8)   KSTEP(8,7)   KSTEP(7,6)   KSTEP(6,5)   KSTEP(5,4)
            KSTEP(4,3)   KSTEP(3,2)   KSTEP(2,1)   KSTEP(1,0)
            if (v > v0) { v0 = v; j0 = j; }
        }
    }
    int* o = idx + ((size_t)b * NP + i) * KNB;
    float hv = v0; int hj = j0;
    for (int r = 0; r < KNB; ++r) {
        float mv = hv; int mj = hj;
#pragma unroll
        for (int s = 1; s <= 8; s <<= 1) {
            float ov = __shfl_xor(mv, s, 64);
            int   oj = __shfl_xor(mj, s, 64);
            if (ov > mv || (ov == mv && oj < mj)) { mv = ov; mj = oj; }
        }
        if (seg == 0) o[r] = mj;
        if (hv == mv && hj == mj) {
            KSHIFT(0,1)   KSHIFT(1,2)   KSHIFT(2,3)   KSHIFT(3,4)   KSHIFT(4,5)
            KSHIFT(5,6)   KSHIFT(6,7)   KSHIFT(7,8)   KSHIFT(8,9)   KSHIFT(9,10)
            KSHIFT(10,11) KSHIFT(11,12) KSHIFT(12,13) KSHIFT(13,14) KSHIFT(14,15)
            KSHIFT(15,16) KSHIFT(16,17) KSHIFT(17,18) KSHIFT(18,19)
            v19 = -3.4e38f; j19 = 0;
        }
        hv = v0; hj = j0;
    }
}

// ==== graph feature, channel-contiguous f[b][s][32]; ch 0-5 real, 6-31 ZERO ====
__global__ void gather_kernel(const float* __restrict__ x, const int* __restrict__ idx,
                              bf16_t* __restrict__ f) {
    int s = blockIdx.x * 256 + threadIdx.x;
    int b = blockIdx.y;
    int n = s / KNB;
    int j = idx[(size_t)b * SS + s];
    const float* xb = x + (size_t)b * 3 * NP;
    ushort4 u0, u1;
    u0.x = f2bf(xb[j]);          u0.y = f2bf(xb[NP + j]);
    u0.z = f2bf(xb[2 * NP + j]); u0.w = f2bf(xb[n]);
    u1.x = f2bf(xb[NP + n]);     u1.y = f2bf(xb[2 * NP + n]);
    u1.z = 0; u1.w = 0;
    ushort4 z4; z4.x = 0; z4.y = 0; z4.z = 0; z4.w = 0;
    bf16_t* fb = f + ((size_t)b * SS + s) * 32;
    *(ushort4*)(fb)      = u0;
    *(ushort4*)(fb + 4)  = u1;
    *(ushort4*)(fb + 8)  = z4;
    *(ushort4*)(fb + 12) = z4;
    *(ushort4*)(fb + 16) = z4;
    *(ushort4*)(fb + 20) = z4;
    *(ushort4*)(fb + 24) = z4;
    *(ushort4*)(fb + 28) = z4;
}

// ==== weights fp32 -> bf16, zero-padded rows ====
__global__ void wconv_kernel(const float* __restrict__ src, bf16_t* __restrict__ dst,
                             int O, int CI, int CIP) {
    int t = blockIdx.x * 256 + threadIdx.x;
    if (t >= O * CIP) return;
    int o = t / CIP, cp = t - o * CIP;
    dst[t] = (cp < CI) ? f2bf(src[o * CI + cp]) : (bf16_t)0;
}

// ==== zero the layer-stats accumulators (2048 floats) ====
__global__ void zstats_kernel(float* __restrict__ p) {
    p[blockIdx.x * 256 + threadIdx.x] = 0.f;
}

// ==== elementwise BN+ReLU in place on bf16 activations [.., C contiguous] ====
__global__ void bnrelu_kernel(bf16_t* __restrict__ y, const float* __restrict__ ab,
                              int C) {
    size_t e0 = ((size_t)blockIdx.x * 256 + threadIdx.x) * 8;
    int c0 = (int)(e0 & (size_t)(C - 1));
    uint4 r = *(uint4*)(y + e0);
    float4 a0 = *(const float4*)(ab + c0);
    float4 a1 = *(const float4*)(ab + c0 + 4);
    float4 d0 = *(const float4*)(ab + C + c0);
    float4 d1 = *(const float4*)(ab + C + c0 + 4);
    float v0 = bf2f((unsigned short)(r.x & 0xffffu)), v1 = bf2f((unsigned short)(r.x >> 16));
    float v2 = bf2f((unsigned short)(r.y & 0xffffu)), v3 = bf2f((unsigned short)(r.y >> 16));
    float v4 = bf2f((unsigned short)(r.z & 0xffffu)), v5 = bf2f((unsigned short)(r.z >> 16));
    float v6 = bf2f((unsigned short)(r.w & 0xffffu)), v7 = bf2f((unsigned short)(r.w >> 16));
    v0 = fmaxf(fmaf(a0.x, v0, d0.x), 0.f); v1 = fmaxf(fmaf(a0.y, v1, d0.y), 0.f);
    v2 = fmaxf(fmaf(a0.z, v2, d0.z), 0.f); v3 = fmaxf(fmaf(a0.w, v3, d0.w), 0.f);
    v4 = fmaxf(fmaf(a1.x, v4, d1.x), 0.f); v5 = fmaxf(fmaf(a1.y, v5, d1.y), 0.f);
    v6 = fmaxf(fmaf(a1.z, v6, d1.z), 0.f); v7 = fmaxf(fmaf(a1.w, v7, d1.w), 0.f);
    r.x = (unsigned)f2bf(v0) | ((unsigned)f2bf(v1) << 16);
    r.y = (unsigned)f2bf(v2) | ((unsigned)f2bf(v3) << 16);
    r.z = (unsigned)f2bf(v4) | ((unsigned)f2bf(v5) << 16);
    r.w = (unsigned)f2bf(v6) | ((unsigned)f2bf(v7) << 16);
    *(uint4*)(y + e0) = r;
}

// ==== MFMA conv v2: pure load+MFMA K-loop (BN pre-applied by bnrelu_kernel),
// A-fragments preloaded in explicit registers (PRE, CIN<=128), NS s-tiles per
// block. Wave: 64cout x 32s. Block: NW waves (SR=NW*32 rows per iter).
// Epilogue per iter: bf16 ytile (verified C/D map) -> coalesced store /
// whole-k-group max pool (plain stores) / chunked stats in regs -> atomics once.
#define MF(A, B, C) C = __builtin_amdgcn_mfma_f32_16x16x32_bf16(A, B, C, 0, 0, 0);

#define KMFMA(AK0, AK1, AK2, AK3, koff) { \
    short8_t bb0 = *(const short8_t*)(hp0 + (koff)); \
    short8_t bb1 = *(const short8_t*)(hp1 + (koff)); \
    MF(AK0, bb0, c00) MF(AK1, bb0, c10) MF(AK2, bb0, c20) MF(AK3, bb0, c30) \
    MF(AK0, bb1, c01) MF(AK1, bb1, c11) MF(AK2, bb1, c21) MF(AK3, bb1, c31) }

#define TILE1(CC, CT, STt) { \
    bf16_t* tp = &ytile[w * 32 + (STt) * 16 + col][(CT) * 16 + quad * 4]; \
    tp[0] = f2bf(CC[0]); tp[1] = f2bf(CC[1]); \
    tp[2] = f2bf(CC[2]); tp[3] = f2bf(CC[3]); }

template<int CIN, int COUT_T, int SROWS, int NW, int NS, bool POOL, bool ST, bool PRE>
__global__ void mconv(const bf16_t* __restrict__ H, const bf16_t* __restrict__ Wb,
                      bf16_t* __restrict__ Yout, bf16_t* __restrict__ poolOut,
                      int chofs, float* __restrict__ stats) {
    constexpr int SR = NW * 32;
    __shared__ bf16_t ytile[SR][68];
    __shared__ float redS[NW][64];
    __shared__ float redQ[NW][64];
    const int tid  = threadIdx.x;
    const int lane = tid & 63, col = lane & 15, quad = lane >> 4, q8 = quad * 8;
    const int w    = tid >> 6;
    const int cob  = blockIdx.y * 64;
    const int b    = blockIdx.z;
    const bf16_t* wp = Wb + (size_t)(cob + col) * CIN + q8;

    // A-fragment preload (explicit scalars -- no arrays, no spill)
    short8_t A00 = {}, A10 = {}, A20 = {}, A30 = {};
    short8_t A01 = {}, A11 = {}, A21 = {}, A31 = {};
    short8_t A02 = {}, A12 = {}, A22 = {}, A32 = {};
    short8_t A03 = {}, A13 = {}, A23 = {}, A33 = {};
    if constexpr (PRE) {
        A00 = *(const short8_t*)(wp);
        A10 = *(const short8_t*)(wp + 16 * CIN);
        A20 = *(const short8_t*)(wp + 32 * CIN);
        A30 = *(const short8_t*)(wp + 48 * CIN);
        if constexpr (CIN >= 64) {
            A01 = *(const short8_t*)(wp + 32);
            A11 = *(const short8_t*)(wp + 16 * CIN + 32);
            A21 = *(const short8_t*)(wp + 32 * CIN + 32);
            A31 = *(const short8_t*)(wp + 48 * CIN + 32);
        }
        if constexpr (CIN >= 128) {
            A02 = *(const short8_t*)(wp + 64);
            A12 = *(const short8_t*)(wp + 16 * CIN + 64);
            A22 = *(const short8_t*)(wp + 32 * CIN + 64);
            A32 = *(const short8_t*)(wp + 48 * CIN + 64);
            A03 = *(const short8_t*)(wp + 96);
            A13 = *(const short8_t*)(wp + 16 * CIN + 96);
            A23 = *(const short8_t*)(wp + 32 * CIN + 96);
            A33 = *(const short8_t*)(wp + 48 * CIN + 96);
        }
    }

    float svT = 0.f, qvT = 0.f;
    const int cS = tid & 63, chS = tid >> 6;

    for (int it = 0; it < NS; ++it) {
        const int sb = blockIdx.x * (SR * NS) + it * SR + w * 32;
        const bf16_t* hp0 = H + ((size_t)b * SROWS + sb + col) * CIN + q8;
        const bf16_t* hp1 = hp0 + 16 * CIN;

        f32x4 c00 = {0.f,0.f,0.f,0.f}, c10 = c00, c20 = c00, c30 = c00;
        f32x4 c01 = c00, c11 = c00, c21 = c00, c31 = c00;

        if constexpr (PRE) {
            KMFMA(A00, A10, A20, A30, 0)
            if constexpr (CIN >= 64)  KMFMA(A01, A11, A21, A31, 32)
            if constexpr (CIN >= 128) {
                KMFMA(A02, A12, A22, A32, 64)
                KMFMA(A03, A13, A23, A33, 96)
            }
        } else {
#pragma unroll 4
            for (int k0 = 0; k0 < CIN; k0 += 32) {
                short8_t a0 = *(const short8_t*)(wp + k0);
                short8_t a1 = *(const short8_t*)(wp + 16 * CIN + k0);
                short8_t a2 = *(const short8_t*)(wp + 32 * CIN + k0);
                short8_t a3 = *(const short8_t*)(wp + 48 * CIN + k0);
                KMFMA(a0, a1, a2, a3, k0)
            }
        }

        TILE1(c00,0,0) TILE1(c10,1,0) TILE1(c20,2,0) TILE1(c30,3,0)
        TILE1(c01,0,1) TILE1(c11,1,1) TILE1(c21,2,1) TILE1(c31,3,1)
        __syncthreads();

        if constexpr (ST) {
            const int row0 = blockIdx.x * (SR * NS) + it * SR;
            for (int i = tid; i < SR * 16; i += NW * 64) {
                int row = i >> 4, c4 = (i & 15) * 4;
                *(ushort4*)(Yout + ((size_t)b * SROWS + row0 + row) * COUT_T + cob + c4)
                    = *(const ushort4*)&ytile[row][c4];
            }
        }
        if constexpr (POOL) {   // SR=160 = exactly 8 whole k-groups
            const int nbase = (blockIdx.x * NS + it) * 8;
            for (int i = tid; i < 8 * 64; i += NW * 64) {
                int nl = i >> 6, c = i & 63;
                float m = bf2f(ytile[nl * 20][c]);
#pragma unroll
                for (int k = 1; k < KNB; ++k) m = fmaxf(m, bf2f(ytile[nl * 20 + k][c]));
                poolOut[((size_t)b * NP + nbase + nl) * 512 + chofs + cob + c] = f2bf(m);
            }
        }
        // stats chunk: rows [chS*32, chS*32+32) of this iter's tile
        for (int s = chS * 32; s < chS * 32 + 32; ++s) {
            float v = bf2f(ytile[s][cS]);
            svT += v; qvT += v * v;
        }
        __syncthreads();
    }

    redS[chS][cS] = svT; redQ[chS][cS] = qvT;
    __syncthreads();
    if (tid < 64) {
        float sv = 0.f, qv = 0.f;
#pragma unroll
        for (int ch = 0; ch < NW; ++ch) { sv += redS[ch][tid]; qv += redQ[ch][tid]; }
        atomicAdd(&stats[cob + tid], sv);
        atomicAdd(&stats[COUT_T + cob + tid], qv);
    }
}

// ==== summed stats -> BN affine coefs ====
__global__ void bn_finalize(const float* __restrict__ stats,
                            const float* __restrict__ g, const float* __restrict__ bt,
                            float* __restrict__ ab, int C, float invM) {
    int c = blockIdx.x * 64 + threadIdx.x;
    if (c >= C) return;
    float mean = stats[c] * invM;
    float var  = fmaxf(stats[C + c] * invM - mean * mean, 0.f);
    float a = g[c] * rsqrtf(var + 1e-5f);
    ab[c] = a;
    ab[C + c] = fmaf(-mean, a, bt[c]);
}

// ==== pooled raw bf16 -> BN+ReLU -> xcat bf16 [b][n][512] ====
__global__ void pool_convert(const bf16_t* __restrict__ pr, const float* __restrict__ ab,
                             bf16_t* __restrict__ xc, int C, int chofs, int logC) {
    int t = blockIdx.x * 256 + threadIdx.x;
    int c = t & (C - 1);
    int rest = t >> logC;
    int n = rest & (NP - 1);
    int b = rest >> 11;
    size_t p = ((size_t)b * NP + n) * 512 + chofs + c;
    float v = bf2f(pr[p]);
    xc[p] = f2bf(fmaxf(fmaf(ab[c], v, ab[C + c]), 0.f));
}

// ==== y5 bf16 [b][n][512] -> BN+ReLU -> out f32 [b][1024][n] (pad zero) ====
__global__ void out_kernel(const bf16_t* __restrict__ y5, const float* __restrict__ ab,
                           float* __restrict__ out) {
    int t = blockIdx.x * 256 + threadIdx.x;
    int n = t & (NP - 1);
    int c4 = (t >> 11) & 255;
    int b = t >> 19;
    int c0 = c4 * 4;
    float4 v = make_float4(0.f, 0.f, 0.f, 0.f);
    if (c0 < 512) {
        ushort4 yv = *(const ushort4*)(y5 + ((size_t)b * NP + n) * 512 + c0);
        float4 av = *(const float4*)(ab + c0);
        float4 dv = *(const float4*)(ab + 512 + c0);
        v.x = fmaxf(fmaf(av.x, bf2f(yv.x), dv.x), 0.f);
        v.y = fmaxf(fmaf(av.y, bf2f(yv.y), dv.y), 0.f);
        v.z = fmaxf(fmaf(av.z, bf2f(yv.z), dv.z), 0.f);
        v.w = fmaxf(fmaf(av.w, bf2f(yv.w), dv.w), 0.f);
    }
    float* ob = out + ((size_t)b * 1024 + c0) * NP + n;
    ob[0] = v.x; ob[NP] = v.y; ob[2 * NP] = v.z; ob[3 * NP] = v.w;
}

extern "C" void kernel_launch(void* const* d_in, const int* in_sizes, int n_in,
                              void* d_out, int out_size, void* d_ws, size_t ws_size,
                              hipStream_t stream) {
    (void)in_sizes; (void)n_in; (void)out_size; (void)ws_size;
    const float* x  = (const float*)d_in[0];
    const float* W1 = (const float*)d_in[1];
    const float* W2 = (const float*)d_in[2];
    const float* W3 = (const float*)d_in[3];
    const float* W4 = (const float*)d_in[4];
    const float* W5 = (const float*)d_in[5];
    const float* g1 = (const float*)d_in[6];  const float* b1 = (const float*)d_in[7];
    const float* g2 = (const float*)d_in[8];  const float* b2 = (const float*)d_in[9];
    const float* g3 = (const float*)d_in[10]; const float* b3 = (const float*)d_in[11];
    const float* g4 = (const float*)d_in[12]; const float* b4 = (const float*)d_in[13];
    const float* g5 = (const float*)d_in[14]; const float* b5 = (const float*)d_in[15];

    // workspace, lifetime-aliased (R9 arena):
    // A @0: f | y2 | y5(bf16)   B @41943040: y1 | y3
    char* ws = (char*)d_ws;
    bf16_t* f    = (bf16_t*)(ws + 0);
    bf16_t* y2   = (bf16_t*)(ws + 0);
    bf16_t* y5   = (bf16_t*)(ws + 0);
    bf16_t* y1   = (bf16_t*)(ws + 41943040);
    bf16_t* y3   = (bf16_t*)(ws + 41943040);
    bf16_t* poolraw = (bf16_t*)(ws + 125829120);
    bf16_t* xcat    = (bf16_t*)(ws + 142606336);
    bf16_t* Wball   = (bf16_t*)(ws + 159383552);
    bf16_t* W1b = Wball;            // 64x32
    bf16_t* W2b = Wball + 2048;     // 64x64
    bf16_t* W3b = Wball + 6144;     // 128x64
    bf16_t* W4b = Wball + 14336;    // 256x128
    bf16_t* W5b = Wball + 47104;    // 512x512
    float* stats = (float*)(ws + 160002048);
    float* ab    = (float*)(ws + 160010240);
    int*  idx    = (int*)  (ws + 160018432);

    float* st1 = stats;        float* st2 = stats + 128;  float* st3 = stats + 256;
    float* st4 = stats + 512;  float* st5 = stats + 1024;
    float* ab1 = ab;       float* ab2 = ab + 128;  float* ab3 = ab + 256;
    float* ab4 = ab + 512; float* ab5 = ab + 1024;
    const float invM14 = 1.f / (float)(BB * SS);
    const float invM5  = 1.f / (float)(BB * NP);

    zstats_kernel<<<8, 256, 0, stream>>>(stats);
    wconv_kernel<<<8,    256, 0, stream>>>(W1, W1b, 64, 6, 32);
    wconv_kernel<<<16,   256, 0, stream>>>(W2, W2b, 64, 64, 64);
    wconv_kernel<<<32,   256, 0, stream>>>(W3, W3b, 128, 64, 64);
    wconv_kernel<<<128,  256, 0, stream>>>(W4, W4b, 256, 128, 128);
    wconv_kernel<<<1024, 256, 0, stream>>>(W5, W5b, 512, 512, 512);

    knn_kernel<<<1024, 256, 0, stream>>>(x, idx);
    gather_kernel<<<dim3(160, BB), 256, 0, stream>>>(x, idx, f);

    // L1: 6(pad32) -> 64
    mconv<32, 64, SS, 5, 4, true, true, true><<<dim3(64, 1, BB), 320, 0, stream>>>(
        f, W1b, y1, poolraw, 0, st1);
    bn_finalize<<<1, 64, 0, stream>>>(st1, g1, b1, ab1, 64, invM14);
    pool_convert<<<4096, 256, 0, stream>>>(poolraw, ab1, xcat, 64, 0, 6);
    bnrelu_kernel<<<10240, 256, 0, stream>>>(y1, ab1, 64);

    // L2: 64 -> 64
    mconv<64, 64, SS, 5, 4, true, true, true><<<dim3(64, 1, BB), 320, 0, stream>>>(
        y1, W2b, y2, poolraw, 64, st2);
    bn_finalize<<<1, 64, 0, stream>>>(st2, g2, b2, ab2, 64, invM14);
    pool_convert<<<4096, 256, 0, stream>>>(poolraw, ab2, xcat, 64, 64, 6);
    bnrelu_kernel<<<10240, 256, 0, stream>>>(y2, ab2, 64);

    // L3: 64 -> 128
    mconv<64, 128, SS, 5, 4, true, true, true><<<dim3(64, 2, BB), 320, 0, stream>>>(
        y2, W3b, y3, poolraw, 128, st3);
    bn_finalize<<<2, 64, 0, stream>>>(st3, g3, b3, ab3, 128, invM14);
    pool_convert<<<8192, 256, 0, stream>>>(poolraw, ab3, xcat, 128, 128, 7);
    bnrelu_kernel<<<20480, 256, 0, stream>>>(y3, ab3, 128);

    // L4: 128 -> 256, pool-only (y4 never materialized)
    mconv<128, 256, SS, 5, 4, true, false, true><<<dim3(64, 4, BB), 320, 0, stream>>>(
        y3, W4b, nullptr, poolraw, 256, st4);
    bn_finalize<<<4, 64, 0, stream>>>(st4, g4, b4, ab4, 256, invM14);
    pool_convert<<<16384, 256, 0, stream>>>(poolraw, ab4, xcat, 256, 256, 8);

    // L5: 512 -> 512 over [b][2048][512] (xcat already post-BN)
    mconv<512, 512, NP, 4, 1, false, true, false><<<dim3(16, 8, BB), 256, 0, stream>>>(
        xcat, W5b, y5, nullptr, 0, st5);
    bn_finalize<<<8, 64, 0, stream>>>(st5, g5, b5, ab5, 512, invM5);

    out_kernel<<<16384, 256, 0, stream>>>(y5, ab5, (float*)d_out);
}

// Round 11
// 488.873 us; speedup vs baseline: 5.7064x; 1.0923x over previous
//
#include <hip/hip_runtime.h>

#define BB  8
#define NP  2048
#define KNB 20
#define SS  40960   // spatial per batch, layers 1-4

typedef unsigned short bf16_t;
typedef __attribute__((ext_vector_type(8))) short short8_t;   // MFMA A/B frag (8 bf16)
typedef __attribute__((ext_vector_type(4))) float f32x4;      // MFMA C/D frag

static __device__ __forceinline__ float bf2f(unsigned short u) {
    return __uint_as_float(((unsigned)u) << 16);
}
static __device__ __forceinline__ bf16_t f2bf(float f) {
    unsigned u = __float_as_uint(f);
    return (bf16_t)((u + 0x7fffu + ((u >> 16) & 1u)) >> 16);   // RNE
}

#if __has_builtin(__builtin_amdgcn_fmed3f)
#define MED3(a, b, c) __builtin_amdgcn_fmed3f((a), (b), (c))
#else
#define MED3(a, b, c) fmaxf(fminf((a), (b)), fminf(fmaxf((a), (b)), (c)))
#endif

// ==== kNN v3: branchless value-phase (med3 chain) + theta pop-merge +
//      survivor rank-emit. Matches jax.lax.top_k ordering exactly:
//      (value desc, index asc) total order; theta = 20th-largest value.
static __device__ __forceinline__ float negdist(float4 me, float4 p) {
    float d = me.x * p.x + me.y * p.y + me.z * p.z;
    return 2.0f * d - me.w - p.w;
}

#define BDECL(t) float bv##t = -3.4e38f;
#define MCH(t, p) bv##t = MED3(v, bv##p, bv##t);
#define BSHIFT(t, n) bv##t = bv##n;

__global__ __launch_bounds__(256) void knn_kernel(const float* __restrict__ x,
                                                  int* __restrict__ idx) {
    __shared__ float4 tile[2064];      // 2048 + (j>>7) swizzle pad, 33 KB
    __shared__ int   cnt[16];
    __shared__ float svv[16][44];
    __shared__ int   svj[16][44];
    const int tid  = threadIdx.x;
    const int b    = blockIdx.x >> 7;
    const int pblk = blockIdx.x & 127;
    const int pl   = tid >> 4;         // local point 0..15
    const int seg  = tid & 15;         // segment 0..15 (128 cands each)
    const int i    = pblk * 16 + pl;
    const float* xb = x + (size_t)b * 3 * NP;

    for (int j = tid; j < NP; j += 256) {
        float a0 = xb[j], a1 = xb[NP + j], a2 = xb[2 * NP + j];
        tile[j + (j >> 7)] = make_float4(a0, a1, a2, a0 * a0 + a1 * a1 + a2 * a2);
    }
    if (tid < 16) cnt[tid] = 0;
    __syncthreads();
    const float4 me = tile[i + (i >> 7)];
    const float4* tseg = &tile[seg * 129];

    // ---- phase 1: per-lane top-20 VALUES, branchless med3 ripple ----
    BDECL(0)  BDECL(1)  BDECL(2)  BDECL(3)  BDECL(4)
    BDECL(5)  BDECL(6)  BDECL(7)  BDECL(8)  BDECL(9)
    BDECL(10) BDECL(11) BDECL(12) BDECL(13) BDECL(14)
    BDECL(15) BDECL(16) BDECL(17) BDECL(18) BDECL(19)
    for (int t = 0; t < 128; ++t) {
        float v = negdist(me, tseg[t]);
        MCH(19,18) MCH(18,17) MCH(17,16) MCH(16,15) MCH(15,14)
        MCH(14,13) MCH(13,12) MCH(12,11) MCH(11,10) MCH(10,9)
        MCH(9,8)   MCH(8,7)   MCH(7,6)   MCH(6,5)   MCH(5,4)
        MCH(4,3)   MCH(3,2)   MCH(2,1)   MCH(1,0)
        bv0 = fmaxf(bv0, v);
    }

    // ---- theta: 20 rounds of 16-lane argmax-with-pop (values only) ----
    float theta = -3.4e38f;
    for (int r = 0; r < KNB; ++r) {
        float mv = bv0; int ms = seg;
#pragma unroll
        for (int s = 1; s <= 8; s <<= 1) {
            float ov = __shfl_xor(mv, s, 64);
            int   os = __shfl_xor(ms, s, 64);
            if (ov > mv || (ov == mv && os < ms)) { mv = ov; ms = os; }
        }
        if (seg == ms) {   // exactly one lane pops its head
            BSHIFT(0,1)   BSHIFT(1,2)   BSHIFT(2,3)   BSHIFT(3,4)   BSHIFT(4,5)
            BSHIFT(5,6)   BSHIFT(6,7)   BSHIFT(7,8)   BSHIFT(8,9)   BSHIFT(9,10)
            BSHIFT(10,11) BSHIFT(11,12) BSHIFT(12,13) BSHIFT(13,14) BSHIFT(14,15)
            BSHIFT(15,16) BSHIFT(16,17) BSHIFT(17,18) BSHIFT(18,19)
            bv19 = -3.4e38f;
        }
        theta = mv;        // after round 19: the 20th-largest value
    }

    // ---- phase 2: collect survivors (v >= theta), identical arithmetic ----
    for (int t = 0; t < 128; ++t) {
        float v = negdist(me, tseg[t]);
        if (v >= theta) {
            int k = atomicAdd(&cnt[pl], 1);
            if (k < 44) { svv[pl][k] = v; svj[pl][k] = seg * 128 + t; }
        }
    }
    __syncthreads();

    // ---- emit: rank = #{(v',j') : v'>v or (v'==v && j'<j)} ----
    int n = cnt[pl]; if (n > 44) n = 44;
    int* o = idx + ((size_t)b * NP + i) * KNB;
    for (int e = seg; e < n; e += 16) {
        float v = svv[pl][e]; int j = svj[pl][e];
        int rank = 0;
        for (int q = 0; q < n; ++q) {
            float vq = svv[pl][q]; int jq = svj[pl][q];
            rank += (vq > v || (vq == v && jq < j)) ? 1 : 0;
        }
        if (rank < KNB) o[rank] = j;
    }
}

// ==== graph feature, channel-contiguous f[b][s][32]; ch 0-5 real, 6-31 ZERO ====
__global__ void gather_kernel(const float* __restrict__ x, const int* __restrict__ idx,
                              bf16_t* __restrict__ f) {
    int s = blockIdx.x * 256 + threadIdx.x;
    int b = blockIdx.y;
    int n = s / KNB;
    int j = idx[(size_t)b * SS + s];
    const float* xb = x + (size_t)b * 3 * NP;
    ushort4 u0, u1;
    u0.x = f2bf(xb[j]);          u0.y = f2bf(xb[NP + j]);
    u0.z = f2bf(xb[2 * NP + j]); u0.w = f2bf(xb[n]);
    u1.x = f2bf(xb[NP + n]);     u1.y = f2bf(xb[2 * NP + n]);
    u1.z = 0; u1.w = 0;
    ushort4 z4; z4.x = 0; z4.y = 0; z4.z = 0; z4.w = 0;
    bf16_t* fb = f + ((size_t)b * SS + s) * 32;
    *(ushort4*)(fb)      = u0;
    *(ushort4*)(fb + 4)  = u1;
    *(ushort4*)(fb + 8)  = z4;
    *(ushort4*)(fb + 12) = z4;
    *(ushort4*)(fb + 16) = z4;
    *(ushort4*)(fb + 20) = z4;
    *(ushort4*)(fb + 24) = z4;
    *(ushort4*)(fb + 28) = z4;
}

// ==== weights fp32 -> bf16, zero-padded rows ====
__global__ void wconv_kernel(const float* __restrict__ src, bf16_t* __restrict__ dst,
                             int O, int CI, int CIP) {
    int t = blockIdx.x * 256 + threadIdx.x;
    if (t >= O * CIP) return;
    int o = t / CIP, cp = t - o * CIP;
    dst[t] = (cp < CI) ? f2bf(src[o * CI + cp]) : (bf16_t)0;
}

// ==== zero the layer-stats accumulators (2048 floats) ====
__global__ void zstats_kernel(float* __restrict__ p) {
    p[blockIdx.x * 256 + threadIdx.x] = 0.f;
}

// ==== elementwise BN+ReLU in place on bf16 activations [.., C contiguous] ====
__global__ void bnrelu_kernel(bf16_t* __restrict__ y, const float* __restrict__ ab,
                              int C) {
    size_t e0 = ((size_t)blockIdx.x * 256 + threadIdx.x) * 8;
    int c0 = (int)(e0 & (size_t)(C - 1));
    uint4 r = *(uint4*)(y + e0);
    float4 a0 = *(const float4*)(ab + c0);
    float4 a1 = *(const float4*)(ab + c0 + 4);
    float4 d0 = *(const float4*)(ab + C + c0);
    float4 d1 = *(const float4*)(ab + C + c0 + 4);
    float v0 = bf2f((unsigned short)(r.x & 0xffffu)), v1 = bf2f((unsigned short)(r.x >> 16));
    float v2 = bf2f((unsigned short)(r.y & 0xffffu)), v3 = bf2f((unsigned short)(r.y >> 16));
    float v4 = bf2f((unsigned short)(r.z & 0xffffu)), v5 = bf2f((unsigned short)(r.z >> 16));
    float v6 = bf2f((unsigned short)(r.w & 0xffffu)), v7 = bf2f((unsigned short)(r.w >> 16));
    v0 = fmaxf(fmaf(a0.x, v0, d0.x), 0.f); v1 = fmaxf(fmaf(a0.y, v1, d0.y), 0.f);
    v2 = fmaxf(fmaf(a0.z, v2, d0.z), 0.f); v3 = fmaxf(fmaf(a0.w, v3, d0.w), 0.f);
    v4 = fmaxf(fmaf(a1.x, v4, d1.x), 0.f); v5 = fmaxf(fmaf(a1.y, v5, d1.y), 0.f);
    v6 = fmaxf(fmaf(a1.z, v6, d1.z), 0.f); v7 = fmaxf(fmaf(a1.w, v7, d1.w), 0.f);
    r.x = (unsigned)f2bf(v0) | ((unsigned)f2bf(v1) << 16);
    r.y = (unsigned)f2bf(v2) | ((unsigned)f2bf(v3) << 16);
    r.z = (unsigned)f2bf(v4) | ((unsigned)f2bf(v5) << 16);
    r.w = (unsigned)f2bf(v6) | ((unsigned)f2bf(v7) << 16);
    *(uint4*)(y + e0) = r;
}

// ==== MFMA conv (unchanged from R10): pure load+MFMA K-loop, preloaded A
// fragments (PRE, CIN<=128), NS s-tiles per block, bf16 ytile epilogue ====
#define MF(A, B, C) C = __builtin_amdgcn_mfma_f32_16x16x32_bf16(A, B, C, 0, 0, 0);

#define KMFMA(AK0, AK1, AK2, AK3, koff) { \
    short8_t bb0 = *(const short8_t*)(hp0 + (koff)); \
    short8_t bb1 = *(const short8_t*)(hp1 + (koff)); \
    MF(AK0, bb0, c00) MF(AK1, bb0, c10) MF(AK2, bb0, c20) MF(AK3, bb0, c30) \
    MF(AK0, bb1, c01) MF(AK1, bb1, c11) MF(AK2, bb1, c21) MF(AK3, bb1, c31) }

#define TILE1(CC, CT, STt) { \
    bf16_t* tp = &ytile[w * 32 + (STt) * 16 + col][(CT) * 16 + quad * 4]; \
    tp[0] = f2bf(CC[0]); tp[1] = f2bf(CC[1]); \
    tp[2] = f2bf(CC[2]); tp[3] = f2bf(CC[3]); }

template<int CIN, int COUT_T, int SROWS, int NW, int NS, bool POOL, bool ST, bool PRE>
__global__ void mconv(const bf16_t* __restrict__ H, const bf16_t* __restrict__ Wb,
                      bf16_t* __restrict__ Yout, bf16_t* __restrict__ poolOut,
                      int chofs, float* __restrict__ stats) {
    constexpr int SR = NW * 32;
    __shared__ bf16_t ytile[SR][68];
    __shared__ float redS[NW][64];
    __shared__ float redQ[NW][64];
    const int tid  = threadIdx.x;
    const int lane = tid & 63, col = lane & 15, quad = lane >> 4, q8 = quad * 8;
    const int w    = tid >> 6;
    const int cob  = blockIdx.y * 64;
    const int b    = blockIdx.z;
    const bf16_t* wp = Wb + (size_t)(cob + col) * CIN + q8;

    short8_t A00 = {}, A10 = {}, A20 = {}, A30 = {};
    short8_t A01 = {}, A11 = {}, A21 = {}, A31 = {};
    short8_t A02 = {}, A12 = {}, A22 = {}, A32 = {};
    short8_t A03 = {}, A13 = {}, A23 = {}, A33 = {};
    if constexpr (PRE) {
        A00 = *(const short8_t*)(wp);
        A10 = *(const short8_t*)(wp + 16 * CIN);
        A20 = *(const short8_t*)(wp + 32 * CIN);
        A30 = *(const short8_t*)(wp + 48 * CIN);
        if constexpr (CIN >= 64) {
            A01 = *(const short8_t*)(wp + 32);
            A11 = *(const short8_t*)(wp + 16 * CIN + 32);
            A21 = *(const short8_t*)(wp + 32 * CIN + 32);
            A31 = *(const short8_t*)(wp + 48 * CIN + 32);
        }
        if constexpr (CIN >= 128) {
            A02 = *(const short8_t*)(wp + 64);
            A12 = *(const short8_t*)(wp + 16 * CIN + 64);
            A22 = *(const short8_t*)(wp + 32 * CIN + 64);
            A32 = *(const short8_t*)(wp + 48 * CIN + 64);
            A03 = *(const short8_t*)(wp + 96);
            A13 = *(const short8_t*)(wp + 16 * CIN + 96);
            A23 = *(const short8_t*)(wp + 32 * CIN + 96);
            A33 = *(const short8_t*)(wp + 48 * CIN + 96);
        }
    }

    float svT = 0.f, qvT = 0.f;
    const int cS = tid & 63, chS = tid >> 6;

    for (int it = 0; it < NS; ++it) {
        const int sb = blockIdx.x * (SR * NS) + it * SR + w * 32;
        const bf16_t* hp0 = H + ((size_t)b * SROWS + sb + col) * CIN + q8;
        const bf16_t* hp1 = hp0 + 16 * CIN;

        f32x4 c00 = {0.f,0.f,0.f,0.f}, c10 = c00, c20 = c00, c30 = c00;
        f32x4 c01 = c00, c11 = c00, c21 = c00, c31 = c00;

        if constexpr (PRE) {
            KMFMA(A00, A10, A20, A30, 0)
            if constexpr (CIN >= 64)  KMFMA(A01, A11, A21, A31, 32)
            if constexpr (CIN >= 128) {
                KMFMA(A02, A12, A22, A32, 64)
                KMFMA(A03, A13, A23, A33, 96)
            }
        } else {
#pragma unroll 4
            for (int k0 = 0; k0 < CIN; k0 += 32) {
                short8_t a0 = *(const short8_t*)(wp + k0);
                short8_t a1 = *(const short8_t*)(wp + 16 * CIN + k0);
                short8_t a2 = *(const short8_t*)(wp + 32 * CIN + k0);
                short8_t a3 = *(const short8_t*)(wp + 48 * CIN + k0);
                KMFMA(a0, a1, a2, a3, k0)
            }
        }

        TILE1(c00,0,0) TILE1(c10,1,0) TILE1(c20,2,0) TILE1(c30,3,0)
        TILE1(c01,0,1) TILE1(c11,1,1) TILE1(c21,2,1) TILE1(c31,3,1)
        __syncthreads();

        if constexpr (ST) {
            const int row0 = blockIdx.x * (SR * NS) + it * SR;
            for (int i = tid; i < SR * 16; i += NW * 64) {
                int row = i >> 4, c4 = (i & 15) * 4;
                *(ushort4*)(Yout + ((size_t)b * SROWS + row0 + row) * COUT_T + cob + c4)
                    = *(const ushort4*)&ytile[row][c4];
            }
        }
        if constexpr (POOL) {   // SR=160 = exactly 8 whole k-groups
            const int nbase = (blockIdx.x * NS + it) * 8;
            for (int i = tid; i < 8 * 64; i += NW * 64) {
                int nl = i >> 6, c = i & 63;
                float m = bf2f(ytile[nl * 20][c]);
#pragma unroll
                for (int k = 1; k < KNB; ++k) m = fmaxf(m, bf2f(ytile[nl * 20 + k][c]));
                poolOut[((size_t)b * NP + nbase + nl) * 512 + chofs + cob + c] = f2bf(m);
            }
        }
        for (int s = chS * 32; s < chS * 32 + 32; ++s) {
            float v = bf2f(ytile[s][cS]);
            svT += v; qvT += v * v;
        }
        __syncthreads();
    }

    redS[chS][cS] = svT; redQ[chS][cS] = qvT;
    __syncthreads();
    if (tid < 64) {
        float sv = 0.f, qv = 0.f;
#pragma unroll
        for (int ch = 0; ch < NW; ++ch) { sv += redS[ch][tid]; qv += redQ[ch][tid]; }
        atomicAdd(&stats[cob + tid], sv);
        atomicAdd(&stats[COUT_T + cob + tid], qv);
    }
}

// ==== summed stats -> BN affine coefs ====
__global__ void bn_finalize(const float* __restrict__ stats,
                            const float* __restrict__ g, const float* __restrict__ bt,
                            float* __restrict__ ab, int C, float invM) {
    int c = blockIdx.x * 64 + threadIdx.x;
    if (c >= C) return;
    float mean = stats[c] * invM;
    float var  = fmaxf(stats[C + c] * invM - mean * mean, 0.f);
    float a = g[c] * rsqrtf(var + 1e-5f);
    ab[c] = a;
    ab[C + c] = fmaf(-mean, a, bt[c]);
}

// ==== pooled raw bf16 -> BN+ReLU -> xcat bf16 [b][n][512] ====
__global__ void pool_convert(const bf16_t* __restrict__ pr, const float* __restrict__ ab,
                             bf16_t* __restrict__ xc, int C, int chofs, int logC) {
    int t = blockIdx.x * 256 + threadIdx.x;
    int c = t & (C - 1);
    int rest = t >> logC;
    int n = rest & (NP - 1);
    int b = rest >> 11;
    size_t p = ((size_t)b * NP + n) * 512 + chofs + c;
    float v = bf2f(pr[p]);
    xc[p] = f2bf(fmaxf(fmaf(ab[c], v, ab[C + c]), 0.f));
}

// ==== y5 bf16 [b][n][512] -> BN+ReLU -> out f32 [b][1024][n] (pad zero) ====
__global__ void out_kernel(const bf16_t* __restrict__ y5, const float* __restrict__ ab,
                           float* __restrict__ out) {
    int t = blockIdx.x * 256 + threadIdx.x;
    int n = t & (NP - 1);
    int c4 = (t >> 11) & 255;
    int b = t >> 19;
    int c0 = c4 * 4;
    float4 v = make_float4(0.f, 0.f, 0.f, 0.f);
    if (c0 < 512) {
        ushort4 yv = *(const ushort4*)(y5 + ((size_t)b * NP + n) * 512 + c0);
        float4 av = *(const float4*)(ab + c0);
        float4 dv = *(const float4*)(ab + 512 + c0);
        v.x = fmaxf(fmaf(av.x, bf2f(yv.x), dv.x), 0.f);
        v.y = fmaxf(fmaf(av.y, bf2f(yv.y), dv.y), 0.f);
        v.z = fmaxf(fmaf(av.z, bf2f(yv.z), dv.z), 0.f);
        v.w = fmaxf(fmaf(av.w, bf2f(yv.w), dv.w), 0.f);
    }
    float* ob = out + ((size_t)b * 1024 + c0) * NP + n;
    ob[0] = v.x; ob[NP] = v.y; ob[2 * NP] = v.z; ob[3 * NP] = v.w;
}

extern "C" void kernel_launch(void* const* d_in, const int* in_sizes, int n_in,
                              void* d_out, int out_size, void* d_ws, size_t ws_size,
                              hipStream_t stream) {
    (void)in_sizes; (void)n_in; (void)out_size; (void)ws_size;
    const float* x  = (const float*)d_in[0];
    const float* W1 = (const float*)d_in[1];
    const float* W2 = (const float*)d_in[2];
    const float* W3 = (const float*)d_in[3];
    const float* W4 = (const float*)d_in[4];
    const float* W5 = (const float*)d_in[5];
    const float* g1 = (const float*)d_in[6];  const float* b1 = (const float*)d_in[7];
    const float* g2 = (const float*)d_in[8];  const float* b2 = (const float*)d_in[9];
    const float* g3 = (const float*)d_in[10]; const float* b3 = (const float*)d_in[11];
    const float* g4 = (const float*)d_in[12]; const float* b4 = (const float*)d_in[13];
    const float* g5 = (const float*)d_in[14]; const float* b5 = (const float*)d_in[15];

    // workspace, lifetime-aliased (R9 arena):
    // A @0: f | y2 | y5(bf16)   B @41943040: y1 | y3
    char* ws = (char*)d_ws;
    bf16_t* f    = (bf16_t*)(ws + 0);
    bf16_t* y2   = (bf16_t*)(ws + 0);
    bf16_t* y5   = (bf16_t*)(ws + 0);
    bf16_t* y1   = (bf16_t*)(ws + 41943040);
    bf16_t* y3   = (bf16_t*)(ws + 41943040);
    bf16_t* poolraw = (bf16_t*)(ws + 125829120);
    bf16_t* xcat    = (bf16_t*)(ws + 142606336);
    bf16_t* Wball   = (bf16_t*)(ws + 159383552);
    bf16_t* W1b = Wball;            // 64x32
    bf16_t* W2b = Wball + 2048;     // 64x64
    bf16_t* W3b = Wball + 6144;     // 128x64
    bf16_t* W4b = Wball + 14336;    // 256x128
    bf16_t* W5b = Wball + 47104;    // 512x512
    float* stats = (float*)(ws + 160002048);
    float* ab    = (float*)(ws + 160010240);
    int*  idx    = (int*)  (ws + 160018432);

    float* st1 = stats;        float* st2 = stats + 128;  float* st3 = stats + 256;
    float* st4 = stats + 512;  float* st5 = stats + 1024;
    float* ab1 = ab;       float* ab2 = ab + 128;  float* ab3 = ab + 256;
    float* ab4 = ab + 512; float* ab5 = ab + 1024;
    const float invM14 = 1.f / (float)(BB * SS);
    const float invM5  = 1.f / (float)(BB * NP);

    zstats_kernel<<<8, 256, 0, stream>>>(stats);
    wconv_kernel<<<8,    256, 0, stream>>>(W1, W1b, 64, 6, 32);
    wconv_kernel<<<16,   256, 0, stream>>>(W2, W2b, 64, 64, 64);
    wconv_kernel<<<32,   256, 0, stream>>>(W3, W3b, 128, 64, 64);
    wconv_kernel<<<128,  256, 0, stream>>>(W4, W4b, 256, 128, 128);
    wconv_kernel<<<1024, 256, 0, stream>>>(W5, W5b, 512, 512, 512);

    knn_kernel<<<1024, 256, 0, stream>>>(x, idx);
    gather_kernel<<<dim3(160, BB), 256, 0, stream>>>(x, idx, f);

    // L1: 6(pad32) -> 64
    mconv<32, 64, SS, 5, 4, true, true, true><<<dim3(64, 1, BB), 320, 0, stream>>>(
        f, W1b, y1, poolraw, 0, st1);
    bn_finalize<<<1, 64, 0, stream>>>(st1, g1, b1, ab1, 64, invM14);
    pool_convert<<<4096, 256, 0, stream>>>(poolraw, ab1, xcat, 64, 0, 6);
    bnrelu_kernel<<<10240, 256, 0, stream>>>(y1, ab1, 64);

    // L2: 64 -> 64
    mconv<64, 64, SS, 5, 4, true, true, true><<<dim3(64, 1, BB), 320, 0, stream>>>(
        y1, W2b, y2, poolraw, 64, st2);
    bn_finalize<<<1, 64, 0, stream>>>(st2, g2, b2, ab2, 64, invM14);
    pool_convert<<<4096, 256, 0, stream>>>(poolraw, ab2, xcat, 64, 64, 6);
    bnrelu_kernel<<<10240, 256, 0, stream>>>(y2, ab2, 64);

    // L3: 64 -> 128
    mconv<64, 128, SS, 5, 4, true, true, true><<<dim3(64, 2, BB), 320, 0, stream>>>(
        y2, W3b, y3, poolraw, 128, st3);
    bn_finalize<<<2, 64, 0, stream>>>(st3, g3, b3, ab3, 128, invM14);
    pool_convert<<<8192, 256, 0, stream>>>(poolraw, ab3, xcat, 128, 128, 7);
    bnrelu_kernel<<<20480, 256, 0, stream>>>(y3, ab3, 128);

    // L4: 128 -> 256, pool-only (y4 never materialized)
    mconv<128, 256, SS, 5, 4, true, false, true><<<dim3(64, 4, BB), 320, 0, stream>>>(
        y3, W4b, nullptr, poolraw, 256, st4);
    bn_finalize<<<4, 64, 0, stream>>>(st4, g4, b4, ab4, 256, invM14);
    pool_convert<<<16384, 256, 0, stream>>>(poolraw, ab4, xcat, 256, 256, 8);

    // L5: 512 -> 512 over [b][2048][512] (xcat already post-BN)
    mconv<512, 512, NP, 4, 1, false, true, false><<<dim3(16, 8, BB), 256, 0, stream>>>(
        xcat, W5b, y5, nullptr, 0, st5);
    bn_finalize<<<8, 64, 0, stream>>>(st5, g5, b5, ab5, 512, invM5);

    out_kernel<<<16384, 256, 0, stream>>>(y5, ab5, (float*)d_out);
}